// Round 5
// baseline (1581.540 us; speedup 1.0000x reference)
//
#include <hip/hip_runtime.h>

#define U_NUM   100000
#define I_NUM   50000
#define FCT     64
#define NEDGE   3200000
#define BATCH   16384
#define NROWS   (U_NUM + I_NUM)      // 150000
#define TOTSLOTS (2 * NEDGE)         // 6400000

#define BSH 6                        // 64 rows per bucket
#define NBU 1563                     // ceil(100000/64)
#define NBI 782                      // ceil(50000/64)
#define NBUCK (NBU + NBI)            // 2345
#define CPAD 16

__device__ __forceinline__ unsigned short f2b(float f) {
    unsigned int x = __float_as_uint(f);
    unsigned int r = (x + 0x7FFFu + ((x >> 16) & 1u)) >> 16;   // RNE
    return (unsigned short)r;
}
__device__ __forceinline__ float b2f(unsigned short u) {
    return __uint_as_float(((unsigned int)u) << 16);
}

// ---------------- fp32 -> bf16 table conversion ----------------
__global__ void conv_kernel(const float* __restrict__ in, unsigned short* __restrict__ out, int n4) {
    int t = blockIdx.x * blockDim.x + threadIdx.x;
    if (t >= n4) return;
    float4 v = *reinterpret_cast<const float4*>(in + (size_t)t * 4);
    ushort4 o;
    o.x = f2b(v.x); o.y = f2b(v.y); o.z = f2b(v.z); o.w = f2b(v.w);
    *reinterpret_cast<ushort4*>(out + (size_t)t * 4) = o;
}

// ---------------- per-row histogram ----------------
__global__ void hist_kernel(const int* __restrict__ eu, const int* __restrict__ ei,
                            int* __restrict__ cnt) {
    int t = blockIdx.x * blockDim.x + threadIdx.x;
    if (t >= NEDGE) return;
    atomicAdd(&cnt[eu[t]], 1);
    atomicAdd(&cnt[U_NUM + ei[t]], 1);
}

// ---------------- exclusive scan over NROWS (3 kernels) ----------------
__global__ void scan1_kernel(const int* __restrict__ cnt, int* __restrict__ out,
                             int* __restrict__ bsum) {
    __shared__ int s[256];
    int t = threadIdx.x;
    int base = blockIdx.x * 1024 + t * 4;
    int v[4];
#pragma unroll
    for (int k = 0; k < 4; k++) v[k] = (base + k < NROWS) ? cnt[base + k] : 0;
    int tot = v[0] + v[1] + v[2] + v[3];
    s[t] = tot;
    __syncthreads();
    for (int off = 1; off < 256; off <<= 1) {
        int x = (t >= off) ? s[t - off] : 0;
        __syncthreads();
        s[t] += x;
        __syncthreads();
    }
    int p = s[t] - tot;
#pragma unroll
    for (int k = 0; k < 4; k++) {
        if (base + k < NROWS) out[base + k] = p;
        p += v[k];
    }
    if (t == 255) bsum[blockIdx.x] = s[255];
}

__global__ void scan2_kernel(int* __restrict__ bsum, int nb) {
    __shared__ int s[256];
    int t = threadIdx.x;
    int v = (t < nb) ? bsum[t] : 0;
    s[t] = v;
    __syncthreads();
    for (int off = 1; off < 256; off <<= 1) {
        int x = (t >= off) ? s[t - off] : 0;
        __syncthreads();
        s[t] += x;
        __syncthreads();
    }
    if (t < nb) bsum[t] = s[t] - v;
}

__global__ void scan3_kernel(int* __restrict__ rowptr, const int* __restrict__ bsum) {
    int i = blockIdx.x * blockDim.x + threadIdx.x;
    if (i < NROWS) rowptr[i] += bsum[i >> 10];
    if (i == NROWS) rowptr[NROWS] = TOTSLOTS;
}

// ---------------- phase A: XCD-class append of COMPRESSED 4B slots ----------------
// slot = (row_off:6 << 22) | edge_id:22. Class = bucket & 7; block handles only its
// class so each staging line's writers live on one XCD. Class staging region =
// 25.6MB/8 = 3.2MB < 4MB L2 -> lines fill completely before writeback (amp ~1x).
__global__ void __launch_bounds__(256) xscatter_kernel(
        const int* __restrict__ eu, const int* __restrict__ ei,
        const int* __restrict__ rowptr, int* __restrict__ bfill,
        unsigned int* __restrict__ staging) {
    int cls = blockIdx.x & 7;
    int sub = blockIdx.x >> 3;           // 0..255
    for (int t = sub * 256 + (int)threadIdx.x; t < NEDGE; t += 256 * 256) {
        int u = eu[t], i = ei[t];
        int bu = u >> BSH;
        if ((bu & 7) == cls) {
            int slot = rowptr[bu << BSH] + atomicAdd(&bfill[bu * CPAD], 1);
            staging[slot] = ((unsigned int)(u & 63) << 22) | (unsigned int)t;
        }
        int bid = NBU + (i >> BSH);
        if ((bid & 7) == cls) {
            int slot = rowptr[U_NUM + ((i >> BSH) << BSH)] + atomicAdd(&bfill[bid * CPAD], 1);
            staging[slot] = ((unsigned int)(i & 63) << 22) | (unsigned int)t;
        }
    }
}

// ---------------- phase B: per-bucket re-scatter into exact row-CSR order ----------------
__global__ void __launch_bounds__(256) rsort_kernel(const int* __restrict__ rowptr,
                                                    const unsigned int* __restrict__ staging,
                                                    const int* __restrict__ eu,
                                                    const int* __restrict__ ei,
                                                    const float* __restrict__ vui,
                                                    const float* __restrict__ viu,
                                                    int2* __restrict__ csr) {
    __shared__ int fillr[64];
    __shared__ int rp[65];
    int b = blockIdx.x;
    int gRowBase, rows;
    const int* srcArr;
    const float* valArr;
    if (b < NBU) {
        gRowBase = b << BSH;
        rows = min(64, U_NUM - gRowBase);
        srcArr = ei; valArr = vui;
    } else {
        int rb = (b - NBU) << BSH;
        gRowBase = U_NUM + rb;
        rows = min(64, I_NUM - rb);
        srcArr = eu; valArr = viu;
    }
    for (int t = threadIdx.x; t < rows; t += 256) fillr[t] = 0;
    for (int t = threadIdx.x; t <= rows; t += 256) rp[t] = rowptr[gRowBase + t];
    __syncthreads();
    int beg = rp[0], end = rp[rows];
    for (int e = beg + threadIdx.x; e < end; e += 256) {
        unsigned int pk = staging[e];
        int off = (int)(pk >> 22);
        int id  = (int)(pk & 0x3FFFFFu);
        int src = srcArr[id];
        float val = valArr[id];
        int dst = rp[off] + atomicAdd(&fillr[off], 1);
        csr[dst] = make_int2(src, __float_as_int(val));
    }
}

// ---------------- propagation: wave per row, register acc, predicated 8-unroll ----------------
__global__ void __launch_bounds__(256) agg_kernel(
        const unsigned short* __restrict__ uprev, const unsigned short* __restrict__ iprev,
        unsigned short* __restrict__ unext, unsigned short* __restrict__ inext,
        const float* __restrict__ di, const float* __restrict__ dj,
        const int* __restrict__ rowptr, const int2* __restrict__ csr) {
    int wid = (blockIdx.x * 256 + threadIdx.x) >> 6;
    int lane = threadIdx.x & 63;
    if (wid >= NROWS) return;
    const unsigned short* selfP;
    const unsigned short* srcT;
    unsigned short* dst;
    float dscale;
    if (wid < U_NUM) {
        selfP = uprev + (size_t)wid * FCT;
        srcT = iprev;
        dst = unext + (size_t)wid * FCT;
        dscale = di[wid];
    } else {
        int r = wid - U_NUM;
        selfP = iprev + (size_t)r * FCT;
        srcT = uprev;
        dst = inext + (size_t)r * FCT;
        dscale = dj[r];
    }
    int beg = rowptr[wid], end = rowptr[wid + 1];
    float acc = b2f(selfP[lane]) * dscale;
    for (int e = beg; e < end; e += 8) {
        int2 p[8];
        float w[8], g[8];
#pragma unroll
        for (int k = 0; k < 8; k++) {
            int idx = e + k;
            bool ok = idx < end;
            int2 pp = csr[ok ? idx : end - 1];
            p[k] = pp;
            w[k] = ok ? __int_as_float(pp.y) : 0.0f;
        }
#pragma unroll
        for (int k = 0; k < 8; k++) g[k] = b2f(srcT[(size_t)p[k].x * FCT + lane]);
#pragma unroll
        for (int k = 0; k < 8; k++) acc = fmaf(w[k], g[k], acc);
    }
    dst[lane] = f2b(acc);
}

// ---------------- BPR head ----------------
__global__ void __launch_bounds__(256) batch_kernel(
        const float* __restrict__ u0f, const float* __restrict__ i0f,
        const unsigned short* __restrict__ u1, const unsigned short* __restrict__ u2,
        const unsigned short* __restrict__ u3,
        const unsigned short* __restrict__ i1, const unsigned short* __restrict__ i2,
        const unsigned short* __restrict__ i3,
        const int* __restrict__ user, const int* __restrict__ ita, const int* __restrict__ itb,
        float* __restrict__ out, float* __restrict__ ls, float* __restrict__ l2a) {
    int wid = (blockIdx.x * 256 + threadIdx.x) >> 6;
    int lane = threadIdx.x & 63;
    if (wid >= BATCH) return;
    size_t uo = (size_t)user[wid] * FCT + lane;
    size_t ao = (size_t)ita[wid] * FCT + lane;
    size_t bo = (size_t)itb[wid] * FCT + lane;

    float pi, pj, l2;
    {
        float ue = u0f[uo], ie = i0f[ao], je = i0f[bo];
        pi = ue * ie; pj = ue * je; l2 = ue * ue + ie * ie + je * je;
    }
    const unsigned short* Ut[3] = {u1, u2, u3};
    const unsigned short* It[3] = {i1, i2, i3};
#pragma unroll
    for (int l = 0; l < 3; l++) {
        float ue = b2f(Ut[l][uo]), ie = b2f(It[l][ao]), je = b2f(It[l][bo]);
        pi += ue * ie;
        pj += ue * je;
        l2 += ue * ue + ie * ie + je * je;
    }
#pragma unroll
    for (int off = 32; off; off >>= 1) {
        pi += __shfl_xor(pi, off);
        pj += __shfl_xor(pj, off);
        l2 += __shfl_xor(l2, off);
    }
    if (lane == 0) {
        out[wid] = pi;
        out[BATCH + wid] = pj;
        float x = pi - pj;
        ls[wid] = fminf(x, 0.0f) - log1pf(expf(-fabsf(x)));
        l2a[wid] = 0.01f * l2;
    }
}

__global__ void final_kernel(const float* __restrict__ ls, const float* __restrict__ l2a,
                             float* __restrict__ out) {
    __shared__ float s1[256], s2[256];
    int t = threadIdx.x;
    float a = 0.f, b = 0.f;
    for (int i = t; i < BATCH; i += 256) {
        a += ls[i];
        b += l2a[i];
    }
    s1[t] = a;
    s2[t] = b;
    __syncthreads();
    for (int off = 128; off; off >>= 1) {
        if (t < off) {
            s1[t] += s1[t + off];
            s2[t] += s2[t + off];
        }
        __syncthreads();
    }
    if (t == 0) {
        float loss2 = -s1[0] / (float)BATCH;
        float l2m = s2[0] / (float)BATCH;
        out[2 * BATCH] = loss2 + l2m;
        out[2 * BATCH + 1] = loss2;
    }
}

// ---------------- launch ----------------
extern "C" void kernel_launch(void* const* d_in, const int* in_sizes, int n_in,
                              void* d_out, int out_size, void* d_ws, size_t ws_size,
                              hipStream_t stream) {
    const float* u0f = (const float*)d_in[0];
    const float* i0f = (const float*)d_in[1];
    const float* di  = (const float*)d_in[2];
    const float* dj  = (const float*)d_in[3];
    const float* vui = (const float*)d_in[4];
    const float* viu = (const float*)d_in[5];
    const int*   eu  = (const int*)d_in[6];
    const int*   ei  = (const int*)d_in[7];
    const int*   usr = (const int*)d_in[8];
    const int*   ita = (const int*)d_in[9];
    const int*   itb = (const int*)d_in[10];
    float* out = (float*)d_out;

    char* p = (char*)d_ws;
    auto alloc = [&](size_t bytes) -> char* {
        char* r = p;
        p += (bytes + 255) & ~(size_t)255;
        return r;
    };
    unsigned short* u0b = (unsigned short*)alloc((size_t)U_NUM * FCT * 2);
    unsigned short* u1b = (unsigned short*)alloc((size_t)U_NUM * FCT * 2);
    unsigned short* u2b = (unsigned short*)alloc((size_t)U_NUM * FCT * 2);
    unsigned short* u3b = (unsigned short*)alloc((size_t)U_NUM * FCT * 2);
    unsigned short* i0b = (unsigned short*)alloc((size_t)I_NUM * FCT * 2);
    unsigned short* i1b = (unsigned short*)alloc((size_t)I_NUM * FCT * 2);
    unsigned short* i2b = (unsigned short*)alloc((size_t)I_NUM * FCT * 2);
    unsigned short* i3b = (unsigned short*)alloc((size_t)I_NUM * FCT * 2);
    int2* csr            = (int2*)alloc((size_t)TOTSLOTS * 8);          // 51.2 MB
    unsigned int* staging = (unsigned int*)alloc((size_t)TOTSLOTS * 4); // 25.6 MB
    int* rowptr = (int*)alloc((size_t)(NROWS + 1) * 4);
    int* cnt    = (int*)alloc((size_t)NROWS * 4);
    int* bsum   = (int*)alloc(256 * 4);
    int* bfill  = (int*)alloc((size_t)NBUCK * CPAD * 4);
    float* ls   = (float*)alloc((size_t)BATCH * 4);
    float* l2a  = (float*)alloc((size_t)BATCH * 4);

    hipMemsetAsync(cnt, 0, (size_t)NROWS * 4, stream);
    hipMemsetAsync(bfill, 0, (size_t)NBUCK * CPAD * 4, stream);

    conv_kernel<<<(U_NUM * FCT / 4 + 255) / 256, 256, 0, stream>>>(u0f, u0b, U_NUM * FCT / 4);
    conv_kernel<<<(I_NUM * FCT / 4 + 255) / 256, 256, 0, stream>>>(i0f, i0b, I_NUM * FCT / 4);

    hist_kernel<<<(NEDGE + 255) / 256, 256, 0, stream>>>(eu, ei, cnt);
    int nb = (NROWS + 1023) / 1024;
    scan1_kernel<<<nb, 256, 0, stream>>>(cnt, rowptr, bsum);
    scan2_kernel<<<1, 256, 0, stream>>>(bsum, nb);
    scan3_kernel<<<(NROWS + 1 + 255) / 256, 256, 0, stream>>>(rowptr, bsum);

    xscatter_kernel<<<2048, 256, 0, stream>>>(eu, ei, rowptr, bfill, staging);
    rsort_kernel<<<NBUCK, 256, 0, stream>>>(rowptr, staging, eu, ei, vui, viu, csr);

    int aggGrid = (NROWS * 64) / 256 + 1;
    agg_kernel<<<aggGrid, 256, 0, stream>>>(u0b, i0b, u1b, i1b, di, dj, rowptr, csr);
    agg_kernel<<<aggGrid, 256, 0, stream>>>(u1b, i1b, u2b, i2b, di, dj, rowptr, csr);
    agg_kernel<<<aggGrid, 256, 0, stream>>>(u2b, i2b, u3b, i3b, di, dj, rowptr, csr);

    batch_kernel<<<(BATCH * 64) / 256, 256, 0, stream>>>(u0f, i0f, u1b, u2b, u3b,
                                                         i1b, i2b, i3b,
                                                         usr, ita, itb, out, ls, l2a);
    final_kernel<<<1, 256, 0, stream>>>(ls, l2a, out);
}

// Round 6
// 1207.505 us; speedup vs baseline: 1.3098x; 1.3098x over previous
//
#include <hip/hip_runtime.h>

#define U_NUM   100000
#define I_NUM   50000
#define FCT     64
#define NEDGE   3200000
#define BATCH   16384
#define NROWS   (U_NUM + I_NUM)      // 150000
#define TOTSLOTS (2 * NEDGE)         // 6400000

#define BSH 6                        // 64 rows per bucket
#define NBU 1563                     // ceil(100000/64)
#define NBI 782                      // ceil(50000/64)
#define NBUCK (NBU + NBI)            // 2345
#define CPAD 16

__device__ __forceinline__ unsigned short f2b(float f) {
    unsigned int x = __float_as_uint(f);
    unsigned int r = (x + 0x7FFFu + ((x >> 16) & 1u)) >> 16;   // RNE
    return (unsigned short)r;
}
__device__ __forceinline__ float b2f(unsigned short u) {
    return __uint_as_float(((unsigned int)u) << 16);
}

// ---------------- fp32 -> bf16 table conversion ----------------
__global__ void conv_kernel(const float* __restrict__ in, unsigned short* __restrict__ out, int n4) {
    int t = blockIdx.x * blockDim.x + threadIdx.x;
    if (t >= n4) return;
    float4 v = *reinterpret_cast<const float4*>(in + (size_t)t * 4);
    ushort4 o;
    o.x = f2b(v.x); o.y = f2b(v.y); o.z = f2b(v.z); o.w = f2b(v.w);
    *reinterpret_cast<ushort4*>(out + (size_t)t * 4) = o;
}

// ---------------- per-row histogram ----------------
__global__ void hist_kernel(const int* __restrict__ eu, const int* __restrict__ ei,
                            int* __restrict__ cnt) {
    int t = blockIdx.x * blockDim.x + threadIdx.x;
    if (t >= NEDGE) return;
    atomicAdd(&cnt[eu[t]], 1);
    atomicAdd(&cnt[U_NUM + ei[t]], 1);
}

// ---------------- exclusive scan over NROWS (3 kernels) ----------------
__global__ void scan1_kernel(const int* __restrict__ cnt, int* __restrict__ out,
                             int* __restrict__ bsum) {
    __shared__ int s[256];
    int t = threadIdx.x;
    int base = blockIdx.x * 1024 + t * 4;
    int v[4];
#pragma unroll
    for (int k = 0; k < 4; k++) v[k] = (base + k < NROWS) ? cnt[base + k] : 0;
    int tot = v[0] + v[1] + v[2] + v[3];
    s[t] = tot;
    __syncthreads();
    for (int off = 1; off < 256; off <<= 1) {
        int x = (t >= off) ? s[t - off] : 0;
        __syncthreads();
        s[t] += x;
        __syncthreads();
    }
    int p = s[t] - tot;
#pragma unroll
    for (int k = 0; k < 4; k++) {
        if (base + k < NROWS) out[base + k] = p;
        p += v[k];
    }
    if (t == 255) bsum[blockIdx.x] = s[255];
}

__global__ void scan2_kernel(int* __restrict__ bsum, int nb) {
    __shared__ int s[256];
    int t = threadIdx.x;
    int v = (t < nb) ? bsum[t] : 0;
    s[t] = v;
    __syncthreads();
    for (int off = 1; off < 256; off <<= 1) {
        int x = (t >= off) ? s[t - off] : 0;
        __syncthreads();
        s[t] += x;
        __syncthreads();
    }
    if (t < nb) bsum[t] = s[t] - v;
}

__global__ void scan3_kernel(int* __restrict__ rowptr, const int* __restrict__ bsum) {
    int i = blockIdx.x * blockDim.x + threadIdx.x;
    if (i < NROWS) rowptr[i] += bsum[i >> 10];
    if (i == NROWS) rowptr[NROWS] = TOTSLOTS;
}

// ---------------- phase A: XCD-pinned, TIME-PHASED append into bucket regions ----------------
// 16 classes = bucket & 15; this launch handles classes with (cls>>3)==phase.
// Block b serves class (phase<<3)|(b&7); with round-robin block->XCD dispatch all
// writers of a class live on one XCD. Per-XCD live staging = 51.2/16 = 3.2MB < 4MB L2.
// Streamed edge reads use nontemporal loads (zero reuse within an XCD) so they do
// NOT evict the staging lines -> lines fill completely, write amp -> ~1x.
__global__ void __launch_bounds__(256) xscatter_kernel(
        const int* __restrict__ eu, const int* __restrict__ ei,
        const float* __restrict__ vui, const float* __restrict__ viu,
        const int* __restrict__ rowptr, int* __restrict__ bfill,
        int2* __restrict__ staging, int phase) {
    int cls = blockIdx.x & 7;
    int sub = blockIdx.x >> 3;           // 0..255
    for (int t = sub * 256 + (int)threadIdx.x; t < NEDGE; t += 256 * 256) {
        int u = __builtin_nontemporal_load(&eu[t]);
        int i = __builtin_nontemporal_load(&ei[t]);
        float va = __builtin_nontemporal_load(&vui[t]);
        float vb = __builtin_nontemporal_load(&viu[t]);
        int bu = u >> BSH;
        if ((bu & 7) == cls && ((bu >> 3) & 1) == phase) {
            int slot = rowptr[bu << BSH] + atomicAdd(&bfill[bu * CPAD], 1);
            staging[slot] = make_int2(((u & 63) << 17) | i, __float_as_int(va));
        }
        int bid = NBU + (i >> BSH);
        if ((bid & 7) == cls && ((bid >> 3) & 1) == phase) {
            int slot = rowptr[U_NUM + ((i >> BSH) << BSH)] + atomicAdd(&bfill[bid * CPAD], 1);
            staging[slot] = make_int2(((i & 63) << 17) | u, __float_as_int(vb));
        }
    }
}

// ---------------- phase B: per-bucket re-scatter into exact row-CSR order ----------------
__global__ void __launch_bounds__(256) rsort_kernel(const int* __restrict__ rowptr,
                                                    const int2* __restrict__ staging,
                                                    int2* __restrict__ csr) {
    __shared__ int fillr[64];
    __shared__ int rp[65];
    int b = blockIdx.x;
    int gRowBase, rows;
    if (b < NBU) {
        gRowBase = b << BSH;
        rows = min(64, U_NUM - gRowBase);
    } else {
        int rb = (b - NBU) << BSH;
        gRowBase = U_NUM + rb;
        rows = min(64, I_NUM - rb);
    }
    for (int t = threadIdx.x; t < rows; t += 256) fillr[t] = 0;
    for (int t = threadIdx.x; t <= rows; t += 256) rp[t] = rowptr[gRowBase + t];
    __syncthreads();
    int beg = rp[0], end = rp[rows];
    for (int e = beg + threadIdx.x; e < end; e += 256) {
        int2 pk = staging[e];
        int off = pk.x >> 17;
        int src = pk.x & 0x1FFFF;
        int dst = rp[off] + atomicAdd(&fillr[off], 1);
        csr[dst] = make_int2(src, pk.y);
    }
}

// ---------------- propagation: wave per row, register acc, 8-unroll + serial tail ----------------
__global__ void __launch_bounds__(256) agg_kernel(
        const unsigned short* __restrict__ uprev, const unsigned short* __restrict__ iprev,
        unsigned short* __restrict__ unext, unsigned short* __restrict__ inext,
        const float* __restrict__ di, const float* __restrict__ dj,
        const int* __restrict__ rowptr, const int2* __restrict__ csr) {
    int wid = (blockIdx.x * 256 + threadIdx.x) >> 6;
    int lane = threadIdx.x & 63;
    if (wid >= NROWS) return;
    const unsigned short* selfP;
    const unsigned short* srcT;
    unsigned short* dst;
    float dscale;
    if (wid < U_NUM) {
        selfP = uprev + (size_t)wid * FCT;
        srcT = iprev;
        dst = unext + (size_t)wid * FCT;
        dscale = di[wid];
    } else {
        int r = wid - U_NUM;
        selfP = iprev + (size_t)r * FCT;
        srcT = uprev;
        dst = inext + (size_t)r * FCT;
        dscale = dj[r];
    }
    int beg = rowptr[wid], end = rowptr[wid + 1];
    float acc = b2f(selfP[lane]) * dscale;
    int e = beg;
    for (; e + 8 <= end; e += 8) {
        int2 p[8];
        float g[8];
#pragma unroll
        for (int k = 0; k < 8; k++) p[k] = csr[e + k];
#pragma unroll
        for (int k = 0; k < 8; k++) g[k] = b2f(srcT[(size_t)p[k].x * FCT + lane]);
#pragma unroll
        for (int k = 0; k < 8; k++) acc = fmaf(__int_as_float(p[k].y), g[k], acc);
    }
    for (; e < end; ++e) {
        int2 p = csr[e];
        acc = fmaf(__int_as_float(p.y), b2f(srcT[(size_t)p.x * FCT + lane]), acc);
    }
    dst[lane] = f2b(acc);
}

// ---------------- BPR head ----------------
__global__ void __launch_bounds__(256) batch_kernel(
        const float* __restrict__ u0f, const float* __restrict__ i0f,
        const unsigned short* __restrict__ u1, const unsigned short* __restrict__ u2,
        const unsigned short* __restrict__ u3,
        const unsigned short* __restrict__ i1, const unsigned short* __restrict__ i2,
        const unsigned short* __restrict__ i3,
        const int* __restrict__ user, const int* __restrict__ ita, const int* __restrict__ itb,
        float* __restrict__ out, float* __restrict__ ls, float* __restrict__ l2a) {
    int wid = (blockIdx.x * 256 + threadIdx.x) >> 6;
    int lane = threadIdx.x & 63;
    if (wid >= BATCH) return;
    size_t uo = (size_t)user[wid] * FCT + lane;
    size_t ao = (size_t)ita[wid] * FCT + lane;
    size_t bo = (size_t)itb[wid] * FCT + lane;

    float pi, pj, l2;
    {
        float ue = u0f[uo], ie = i0f[ao], je = i0f[bo];
        pi = ue * ie; pj = ue * je; l2 = ue * ue + ie * ie + je * je;
    }
    const unsigned short* Ut[3] = {u1, u2, u3};
    const unsigned short* It[3] = {i1, i2, i3};
#pragma unroll
    for (int l = 0; l < 3; l++) {
        float ue = b2f(Ut[l][uo]), ie = b2f(It[l][ao]), je = b2f(It[l][bo]);
        pi += ue * ie;
        pj += ue * je;
        l2 += ue * ue + ie * ie + je * je;
    }
#pragma unroll
    for (int off = 32; off; off >>= 1) {
        pi += __shfl_xor(pi, off);
        pj += __shfl_xor(pj, off);
        l2 += __shfl_xor(l2, off);
    }
    if (lane == 0) {
        out[wid] = pi;
        out[BATCH + wid] = pj;
        float x = pi - pj;
        ls[wid] = fminf(x, 0.0f) - log1pf(expf(-fabsf(x)));
        l2a[wid] = 0.01f * l2;
    }
}

__global__ void final_kernel(const float* __restrict__ ls, const float* __restrict__ l2a,
                             float* __restrict__ out) {
    __shared__ float s1[256], s2[256];
    int t = threadIdx.x;
    float a = 0.f, b = 0.f;
    for (int i = t; i < BATCH; i += 256) {
        a += ls[i];
        b += l2a[i];
    }
    s1[t] = a;
    s2[t] = b;
    __syncthreads();
    for (int off = 128; off; off >>= 1) {
        if (t < off) {
            s1[t] += s1[t + off];
            s2[t] += s2[t + off];
        }
        __syncthreads();
    }
    if (t == 0) {
        float loss2 = -s1[0] / (float)BATCH;
        float l2m = s2[0] / (float)BATCH;
        out[2 * BATCH] = loss2 + l2m;
        out[2 * BATCH + 1] = loss2;
    }
}

// ---------------- launch ----------------
extern "C" void kernel_launch(void* const* d_in, const int* in_sizes, int n_in,
                              void* d_out, int out_size, void* d_ws, size_t ws_size,
                              hipStream_t stream) {
    const float* u0f = (const float*)d_in[0];
    const float* i0f = (const float*)d_in[1];
    const float* di  = (const float*)d_in[2];
    const float* dj  = (const float*)d_in[3];
    const float* vui = (const float*)d_in[4];
    const float* viu = (const float*)d_in[5];
    const int*   eu  = (const int*)d_in[6];
    const int*   ei  = (const int*)d_in[7];
    const int*   usr = (const int*)d_in[8];
    const int*   ita = (const int*)d_in[9];
    const int*   itb = (const int*)d_in[10];
    float* out = (float*)d_out;

    char* p = (char*)d_ws;
    auto alloc = [&](size_t bytes) -> char* {
        char* r = p;
        p += (bytes + 255) & ~(size_t)255;
        return r;
    };
    unsigned short* u0b = (unsigned short*)alloc((size_t)U_NUM * FCT * 2);
    unsigned short* u1b = (unsigned short*)alloc((size_t)U_NUM * FCT * 2);
    unsigned short* i0b = (unsigned short*)alloc((size_t)I_NUM * FCT * 2);
    unsigned short* i1b = (unsigned short*)alloc((size_t)I_NUM * FCT * 2);
    int2* csr     = (int2*)alloc((size_t)TOTSLOTS * 8);          // 51.2 MB
    int2* staging = (int2*)alloc((size_t)TOTSLOTS * 8);          // 51.2 MB
    int* rowptr = (int*)alloc((size_t)(NROWS + 1) * 4);
    int* cnt    = (int*)alloc((size_t)NROWS * 4);
    int* bsum   = (int*)alloc(256 * 4);
    int* bfill  = (int*)alloc((size_t)NBUCK * CPAD * 4);
    float* ls   = (float*)alloc((size_t)BATCH * 4);
    float* l2a  = (float*)alloc((size_t)BATCH * 4);
    // overlay levels 2,3 on staging (dead after rsort; written by later agg launches)
    unsigned short* u2b = (unsigned short*)staging;
    unsigned short* u3b = u2b + (size_t)U_NUM * FCT;
    unsigned short* i2b = u3b + (size_t)U_NUM * FCT;
    unsigned short* i3b = i2b + (size_t)I_NUM * FCT;

    hipMemsetAsync(cnt, 0, (size_t)NROWS * 4, stream);
    hipMemsetAsync(bfill, 0, (size_t)NBUCK * CPAD * 4, stream);

    conv_kernel<<<(U_NUM * FCT / 4 + 255) / 256, 256, 0, stream>>>(u0f, u0b, U_NUM * FCT / 4);
    conv_kernel<<<(I_NUM * FCT / 4 + 255) / 256, 256, 0, stream>>>(i0f, i0b, I_NUM * FCT / 4);

    hist_kernel<<<(NEDGE + 255) / 256, 256, 0, stream>>>(eu, ei, cnt);
    int nb = (NROWS + 1023) / 1024;
    scan1_kernel<<<nb, 256, 0, stream>>>(cnt, rowptr, bsum);
    scan2_kernel<<<1, 256, 0, stream>>>(bsum, nb);
    scan3_kernel<<<(NROWS + 1 + 255) / 256, 256, 0, stream>>>(rowptr, bsum);

    xscatter_kernel<<<2048, 256, 0, stream>>>(eu, ei, vui, viu, rowptr, bfill, staging, 0);
    xscatter_kernel<<<2048, 256, 0, stream>>>(eu, ei, vui, viu, rowptr, bfill, staging, 1);
    rsort_kernel<<<NBUCK, 256, 0, stream>>>(rowptr, staging, csr);

    int aggGrid = (NROWS * 64) / 256 + 1;
    agg_kernel<<<aggGrid, 256, 0, stream>>>(u0b, i0b, u1b, i1b, di, dj, rowptr, csr);
    agg_kernel<<<aggGrid, 256, 0, stream>>>(u1b, i1b, u2b, i2b, di, dj, rowptr, csr);
    agg_kernel<<<aggGrid, 256, 0, stream>>>(u2b, i2b, u3b, i3b, di, dj, rowptr, csr);

    batch_kernel<<<(BATCH * 64) / 256, 256, 0, stream>>>(u0f, i0f, u1b, u2b, u3b,
                                                         i1b, i2b, i3b,
                                                         usr, ita, itb, out, ls, l2a);
    final_kernel<<<1, 256, 0, stream>>>(ls, l2a, out);
}

// Round 8
// 1197.578 us; speedup vs baseline: 1.3206x; 1.0083x over previous
//
#include <hip/hip_runtime.h>

#define U_NUM   100000
#define I_NUM   50000
#define FCT     64
#define NEDGE   3200000
#define BATCH   16384
#define NROWS   (U_NUM + I_NUM)      // 150000
#define TOTSLOTS (2 * NEDGE)         // 6400000

#define BSH 6                        // 64 rows per bucket
#define NBU 1563                     // ceil(100000/64)
#define NBI 782                      // ceil(50000/64)
#define NBUCK (NBU + NBI)            // 2345
#define CPAD 16

__device__ __forceinline__ unsigned short f2b(float f) {
    unsigned int x = __float_as_uint(f);
    unsigned int r = (x + 0x7FFFu + ((x >> 16) & 1u)) >> 16;   // RNE
    return (unsigned short)r;
}
__device__ __forceinline__ float b2f(unsigned short u) {
    return __uint_as_float(((unsigned int)u) << 16);
}

// ---------------- fp32 -> bf16 table conversion ----------------
__global__ void conv_kernel(const float* __restrict__ in, unsigned short* __restrict__ out, int n4) {
    int t = blockIdx.x * blockDim.x + threadIdx.x;
    if (t >= n4) return;
    float4 v = *reinterpret_cast<const float4*>(in + (size_t)t * 4);
    ushort4 o;
    o.x = f2b(v.x); o.y = f2b(v.y); o.z = f2b(v.z); o.w = f2b(v.w);
    *reinterpret_cast<ushort4*>(out + (size_t)t * 4) = o;
}

// ---------------- per-row histogram, XCD-class-replicated counters ----------------
// cnt8[c][row]: class c = blockIdx&7. Each edge is processed by exactly one block
// (grid-stride partition); the block increments ONLY its class copy. Class-c blocks
// round-robin onto one XCD -> each copy's lines are written by one XCD only (L2-local
// atomics, single writeback). Kills R6-hist's 199MB cross-XCD line ping-pong.
__global__ void __launch_bounds__(256) hist8_kernel(const int* __restrict__ eu,
                                                    const int* __restrict__ ei,
                                                    int* __restrict__ cnt8) {
    int* mycnt = cnt8 + (size_t)(blockIdx.x & 7) * NROWS;
    int stride = gridDim.x * 256;
    for (int t = blockIdx.x * 256 + (int)threadIdx.x; t < NEDGE; t += stride) {
        int u = __builtin_nontemporal_load(&eu[t]);
        int i = __builtin_nontemporal_load(&ei[t]);
        atomicAdd(&mycnt[u], 1);
        atomicAdd(&mycnt[U_NUM + i], 1);
    }
}

// ---------------- exclusive scan over NROWS (3 kernels); scan1 sums the 8 copies ----------------
__global__ void scan1_kernel(const int* __restrict__ cnt8, int* __restrict__ out,
                             int* __restrict__ bsum) {
    __shared__ int s[256];
    int t = threadIdx.x;
    int base = blockIdx.x * 1024 + t * 4;
    int v[4];
#pragma unroll
    for (int k = 0; k < 4; k++) {
        int row = base + k;
        int c = 0;
        if (row < NROWS) {
#pragma unroll
            for (int x = 0; x < 8; x++) c += cnt8[(size_t)x * NROWS + row];
        }
        v[k] = c;
    }
    int tot = v[0] + v[1] + v[2] + v[3];
    s[t] = tot;
    __syncthreads();
    for (int off = 1; off < 256; off <<= 1) {
        int x = (t >= off) ? s[t - off] : 0;
        __syncthreads();
        s[t] += x;
        __syncthreads();
    }
    int p = s[t] - tot;
#pragma unroll
    for (int k = 0; k < 4; k++) {
        if (base + k < NROWS) out[base + k] = p;
        p += v[k];
    }
    if (t == 255) bsum[blockIdx.x] = s[255];
}

__global__ void scan2_kernel(int* __restrict__ bsum, int nb) {
    __shared__ int s[256];
    int t = threadIdx.x;
    int v = (t < nb) ? bsum[t] : 0;
    s[t] = v;
    __syncthreads();
    for (int off = 1; off < 256; off <<= 1) {
        int x = (t >= off) ? s[t - off] : 0;
        __syncthreads();
        s[t] += x;
        __syncthreads();
    }
    if (t < nb) bsum[t] = s[t] - v;
}

__global__ void scan3_kernel(int* __restrict__ rowptr, const int* __restrict__ bsum) {
    int i = blockIdx.x * blockDim.x + threadIdx.x;
    if (i < NROWS) rowptr[i] += bsum[i >> 10];
    if (i == NROWS) rowptr[NROWS] = TOTSLOTS;
}

// ---------------- phase A: XCD-pinned, time-phased append into bucket regions ----------------
__global__ void __launch_bounds__(256) xscatter_kernel(
        const int* __restrict__ eu, const int* __restrict__ ei,
        const float* __restrict__ vui, const float* __restrict__ viu,
        const int* __restrict__ rowptr, int* __restrict__ bfill,
        int2* __restrict__ staging, int phase) {
    int cls = blockIdx.x & 7;
    int sub = blockIdx.x >> 3;           // 0..255
    for (int t = sub * 256 + (int)threadIdx.x; t < NEDGE; t += 256 * 256) {
        int u = __builtin_nontemporal_load(&eu[t]);
        int i = __builtin_nontemporal_load(&ei[t]);
        float va = __builtin_nontemporal_load(&vui[t]);
        float vb = __builtin_nontemporal_load(&viu[t]);
        int bu = u >> BSH;
        if ((bu & 7) == cls && ((bu >> 3) & 1) == phase) {
            int slot = rowptr[bu << BSH] + atomicAdd(&bfill[bu * CPAD], 1);
            staging[slot] = make_int2(((u & 63) << 17) | i, __float_as_int(va));
        }
        int bid = NBU + (i >> BSH);
        if ((bid & 7) == cls && ((bid >> 3) & 1) == phase) {
            int slot = rowptr[U_NUM + ((i >> BSH) << BSH)] + atomicAdd(&bfill[bid * CPAD], 1);
            staging[slot] = make_int2(((i & 63) << 17) | u, __float_as_int(vb));
        }
    }
}

// ---------------- phase B: per-bucket re-scatter into exact row-CSR order ----------------
__global__ void __launch_bounds__(256) rsort_kernel(const int* __restrict__ rowptr,
                                                    const int2* __restrict__ staging,
                                                    int2* __restrict__ csr) {
    __shared__ int fillr[64];
    __shared__ int rp[65];
    int b = blockIdx.x;
    int gRowBase, rows;
    if (b < NBU) {
        gRowBase = b << BSH;
        rows = min(64, U_NUM - gRowBase);
    } else {
        int rb = (b - NBU) << BSH;
        gRowBase = U_NUM + rb;
        rows = min(64, I_NUM - rb);
    }
    for (int t = threadIdx.x; t < rows; t += 256) fillr[t] = 0;
    for (int t = threadIdx.x; t <= rows; t += 256) rp[t] = rowptr[gRowBase + t];
    __syncthreads();
    int beg = rp[0], end = rp[rows];
    for (int e = beg + (int)threadIdx.x; e < end; e += 256) {
        int2 pk = staging[e];
        int off = pk.x >> 17;
        int src = pk.x & 0x1FFFF;
        int dst = rp[off] + atomicAdd(&fillr[off], 1);
        csr[dst] = make_int2(src, pk.y);
    }
}

// ---------------- propagation: wave per row, register acc, 8-unroll + serial tail ----------------
__global__ void __launch_bounds__(256) agg_kernel(
        const unsigned short* __restrict__ uprev, const unsigned short* __restrict__ iprev,
        unsigned short* __restrict__ unext, unsigned short* __restrict__ inext,
        const float* __restrict__ di, const float* __restrict__ dj,
        const int* __restrict__ rowptr, const int2* __restrict__ csr) {
    int wid = (blockIdx.x * 256 + threadIdx.x) >> 6;
    int lane = threadIdx.x & 63;
    if (wid >= NROWS) return;
    const unsigned short* selfP;
    const unsigned short* srcT;
    unsigned short* dst;
    float dscale;
    if (wid < U_NUM) {
        selfP = uprev + (size_t)wid * FCT;
        srcT = iprev;
        dst = unext + (size_t)wid * FCT;
        dscale = di[wid];
    } else {
        int r = wid - U_NUM;
        selfP = iprev + (size_t)r * FCT;
        srcT = uprev;
        dst = inext + (size_t)r * FCT;
        dscale = dj[r];
    }
    int beg = rowptr[wid], end = rowptr[wid + 1];
    float acc = b2f(selfP[lane]) * dscale;
    int e = beg;
    for (; e + 8 <= end; e += 8) {
        int2 p[8];
        float g[8];
#pragma unroll
        for (int k = 0; k < 8; k++) p[k] = csr[e + k];
#pragma unroll
        for (int k = 0; k < 8; k++) g[k] = b2f(srcT[(size_t)p[k].x * FCT + lane]);
#pragma unroll
        for (int k = 0; k < 8; k++) acc = fmaf(__int_as_float(p[k].y), g[k], acc);
    }
    for (; e < end; ++e) {
        int2 p = csr[e];
        acc = fmaf(__int_as_float(p.y), b2f(srcT[(size_t)p.x * FCT + lane]), acc);
    }
    dst[lane] = f2b(acc);
}

// ---------------- BPR head ----------------
__global__ void __launch_bounds__(256) batch_kernel(
        const float* __restrict__ u0f, const float* __restrict__ i0f,
        const unsigned short* __restrict__ u1, const unsigned short* __restrict__ u2,
        const unsigned short* __restrict__ u3,
        const unsigned short* __restrict__ i1, const unsigned short* __restrict__ i2,
        const unsigned short* __restrict__ i3,
        const int* __restrict__ user, const int* __restrict__ ita, const int* __restrict__ itb,
        float* __restrict__ out, float* __restrict__ ls, float* __restrict__ l2a) {
    int wid = (blockIdx.x * 256 + threadIdx.x) >> 6;
    int lane = threadIdx.x & 63;
    if (wid >= BATCH) return;
    size_t uo = (size_t)user[wid] * FCT + lane;
    size_t ao = (size_t)ita[wid] * FCT + lane;
    size_t bo = (size_t)itb[wid] * FCT + lane;

    float pi, pj, l2;
    {
        float ue = u0f[uo], ie = i0f[ao], je = i0f[bo];
        pi = ue * ie; pj = ue * je; l2 = ue * ue + ie * ie + je * je;
    }
    const unsigned short* Ut[3] = {u1, u2, u3};
    const unsigned short* It[3] = {i1, i2, i3};
#pragma unroll
    for (int l = 0; l < 3; l++) {
        float ue = b2f(Ut[l][uo]), ie = b2f(It[l][ao]), je = b2f(It[l][bo]);
        pi += ue * ie;
        pj += ue * je;
        l2 += ue * ue + ie * ie + je * je;
    }
#pragma unroll
    for (int off = 32; off; off >>= 1) {
        pi += __shfl_xor(pi, off);
        pj += __shfl_xor(pj, off);
        l2 += __shfl_xor(l2, off);
    }
    if (lane == 0) {
        out[wid] = pi;
        out[BATCH + wid] = pj;
        float x = pi - pj;
        ls[wid] = fminf(x, 0.0f) - log1pf(expf(-fabsf(x)));
        l2a[wid] = 0.01f * l2;
    }
}

__global__ void final_kernel(const float* __restrict__ ls, const float* __restrict__ l2a,
                             float* __restrict__ out) {
    __shared__ float s1[256], s2[256];
    int t = threadIdx.x;
    float a = 0.f, b = 0.f;
    for (int i = t; i < BATCH; i += 256) {
        a += ls[i];
        b += l2a[i];
    }
    s1[t] = a;
    s2[t] = b;
    __syncthreads();
    for (int off = 128; off; off >>= 1) {
        if (t < off) {
            s1[t] += s1[t + off];
            s2[t] += s2[t + off];
        }
        __syncthreads();
    }
    if (t == 0) {
        float loss2 = -s1[0] / (float)BATCH;
        float l2m = s2[0] / (float)BATCH;
        out[2 * BATCH] = loss2 + l2m;
        out[2 * BATCH + 1] = loss2;
    }
}

// ---------------- launch ----------------
extern "C" void kernel_launch(void* const* d_in, const int* in_sizes, int n_in,
                              void* d_out, int out_size, void* d_ws, size_t ws_size,
                              hipStream_t stream) {
    const float* u0f = (const float*)d_in[0];
    const float* i0f = (const float*)d_in[1];
    const float* di  = (const float*)d_in[2];
    const float* dj  = (const float*)d_in[3];
    const float* vui = (const float*)d_in[4];
    const float* viu = (const float*)d_in[5];
    const int*   eu  = (const int*)d_in[6];
    const int*   ei  = (const int*)d_in[7];
    const int*   usr = (const int*)d_in[8];
    const int*   ita = (const int*)d_in[9];
    const int*   itb = (const int*)d_in[10];
    float* out = (float*)d_out;

    char* p = (char*)d_ws;
    auto alloc = [&](size_t bytes) -> char* {
        char* r = p;
        p += (bytes + 255) & ~(size_t)255;
        return r;
    };
    unsigned short* u0b = (unsigned short*)alloc((size_t)U_NUM * FCT * 2);
    unsigned short* u1b = (unsigned short*)alloc((size_t)U_NUM * FCT * 2);
    unsigned short* i0b = (unsigned short*)alloc((size_t)I_NUM * FCT * 2);
    unsigned short* i1b = (unsigned short*)alloc((size_t)I_NUM * FCT * 2);
    int2* csr     = (int2*)alloc((size_t)TOTSLOTS * 8);          // 51.2 MB
    int2* staging = (int2*)alloc((size_t)TOTSLOTS * 8);          // 51.2 MB
    int* rowptr = (int*)alloc((size_t)(NROWS + 1) * 4);
    int* cnt8   = (int*)alloc((size_t)8 * NROWS * 4);            // 4.8 MB
    int* bsum   = (int*)alloc(256 * 4);
    int* bfill  = (int*)alloc((size_t)NBUCK * CPAD * 4);
    float* ls   = (float*)alloc((size_t)BATCH * 4);
    float* l2a  = (float*)alloc((size_t)BATCH * 4);
    // overlay levels 2,3 on staging (dead after rsort; written by later agg launches)
    unsigned short* u2b = (unsigned short*)staging;
    unsigned short* u3b = u2b + (size_t)U_NUM * FCT;
    unsigned short* i2b = u3b + (size_t)U_NUM * FCT;
    unsigned short* i3b = i2b + (size_t)I_NUM * FCT;

    hipMemsetAsync(cnt8, 0, (size_t)8 * NROWS * 4, stream);
    hipMemsetAsync(bfill, 0, (size_t)NBUCK * CPAD * 4, stream);

    conv_kernel<<<(U_NUM * FCT / 4 + 255) / 256, 256, 0, stream>>>(u0f, u0b, U_NUM * FCT / 4);
    conv_kernel<<<(I_NUM * FCT / 4 + 255) / 256, 256, 0, stream>>>(i0f, i0b, I_NUM * FCT / 4);

    hist8_kernel<<<2048, 256, 0, stream>>>(eu, ei, cnt8);
    int nb = (NROWS + 1023) / 1024;
    scan1_kernel<<<nb, 256, 0, stream>>>(cnt8, rowptr, bsum);
    scan2_kernel<<<1, 256, 0, stream>>>(bsum, nb);
    scan3_kernel<<<(NROWS + 1 + 255) / 256, 256, 0, stream>>>(rowptr, bsum);

    xscatter_kernel<<<2048, 256, 0, stream>>>(eu, ei, vui, viu, rowptr, bfill, staging, 0);
    xscatter_kernel<<<2048, 256, 0, stream>>>(eu, ei, vui, viu, rowptr, bfill, staging, 1);
    rsort_kernel<<<NBUCK, 256, 0, stream>>>(rowptr, staging, csr);

    int aggGrid = (NROWS * 64) / 256 + 1;
    agg_kernel<<<aggGrid, 256, 0, stream>>>(u0b, i0b, u1b, i1b, di, dj, rowptr, csr);
    agg_kernel<<<aggGrid, 256, 0, stream>>>(u1b, i1b, u2b, i2b, di, dj, rowptr, csr);
    agg_kernel<<<aggGrid, 256, 0, stream>>>(u2b, i2b, u3b, i3b, di, dj, rowptr, csr);

    batch_kernel<<<(BATCH * 64) / 256, 256, 0, stream>>>(u0f, i0f, u1b, u2b, u3b,
                                                         i1b, i2b, i3b,
                                                         usr, ita, itb, out, ls, l2a);
    final_kernel<<<1, 256, 0, stream>>>(ls, l2a, out);
}

// Round 9
// 1036.768 us; speedup vs baseline: 1.5255x; 1.1551x over previous
//
#include <hip/hip_runtime.h>

#define U_NUM   100000
#define I_NUM   50000
#define FCT     64
#define NEDGE   3200000
#define BATCH   16384
#define NROWS   (U_NUM + I_NUM)      // 150000
#define TOTSLOTS (2 * NEDGE)         // 6400000

#define BSH 6                        // 64 rows per bucket
#define NBU 1563                     // ceil(100000/64)
#define NBI 782                      // ceil(50000/64)
#define NBUCK (NBU + NBI)            // 2345
#define CPAD 16

__device__ __forceinline__ unsigned short f2b(float f) {
    unsigned int x = __float_as_uint(f);
    unsigned int r = (x + 0x7FFFu + ((x >> 16) & 1u)) >> 16;   // RNE
    return (unsigned short)r;
}
__device__ __forceinline__ float b2f(unsigned short u) {
    return __uint_as_float(((unsigned int)u) << 16);
}

// ---------------- fp32 -> bf16 table conversion ----------------
__global__ void conv_kernel(const float* __restrict__ in, unsigned short* __restrict__ out, int n4) {
    int t = blockIdx.x * blockDim.x + threadIdx.x;
    if (t >= n4) return;
    float4 v = *reinterpret_cast<const float4*>(in + (size_t)t * 4);
    ushort4 o;
    o.x = f2b(v.x); o.y = f2b(v.y); o.z = f2b(v.z); o.w = f2b(v.w);
    *reinterpret_cast<ushort4*>(out + (size_t)t * 4) = o;
}

// ---------------- bucket histogram: LDS-private count, full flush to class copy ----------------
// Global atomics are memory-side on gfx950 (~32B write each; R8 evidence), so the fix
// is COUNT reduction: 6.4M LDS atomics (free) + 1.2M flush atomics (38MB) vs hist8's
// 6.4M global atomics (199MB). Each block flushes ALL buckets (R6's bug: it flushed
// only its own class's buckets, discarding 7/8 of counts) into its class-replicated
// copy bcnt8[cls][*]; bscan sums the 8 copies.
__global__ void __launch_bounds__(256) bhist_kernel(const int* __restrict__ eu,
                                                    const int* __restrict__ ei,
                                                    int* __restrict__ bcnt8) {
    __shared__ int lcnt[NBUCK];
    for (int k = threadIdx.x; k < NBUCK; k += 256) lcnt[k] = 0;
    __syncthreads();
    int stride = gridDim.x * 256;
    for (int t = blockIdx.x * 256 + (int)threadIdx.x; t < NEDGE; t += stride) {
        int u = __builtin_nontemporal_load(&eu[t]);
        int i = __builtin_nontemporal_load(&ei[t]);
        atomicAdd(&lcnt[u >> BSH], 1);
        atomicAdd(&lcnt[NBU + (i >> BSH)], 1);
    }
    __syncthreads();
    int* mycnt = bcnt8 + (size_t)(blockIdx.x & 7) * NBUCK;
    for (int k = threadIdx.x; k < NBUCK; k += 256) {
        int v = lcnt[k];
        if (v) atomicAdd(&mycnt[k], v);
    }
}

// ---------------- single-block exclusive scan over NBUCK buckets (sums 8 copies) ----------------
__global__ void bscan_kernel(const int* __restrict__ bcnt8, int* __restrict__ bbase) {
    __shared__ int s[256];
    int t = threadIdx.x;
    int v[10];                          // 256*10 = 2560 >= NBUCK
    int tot = 0;
#pragma unroll
    for (int k = 0; k < 10; k++) {
        int idx = t * 10 + k;
        int c = 0;
        if (idx < NBUCK) {
#pragma unroll
            for (int x = 0; x < 8; x++) c += bcnt8[(size_t)x * NBUCK + idx];
        }
        v[k] = c;
        tot += c;
    }
    s[t] = tot;
    __syncthreads();
    for (int off = 1; off < 256; off <<= 1) {
        int x = (t >= off) ? s[t - off] : 0;
        __syncthreads();
        s[t] += x;
        __syncthreads();
    }
    int p = s[t] - tot;
#pragma unroll
    for (int k = 0; k < 10; k++) {
        int idx = t * 10 + k;
        if (idx < NBUCK) bbase[idx] = p;
        p += v[k];
    }
    if (t == 255) bbase[NBUCK] = TOTSLOTS;
}

// ---------------- phase A: XCD-pinned, time-phased append into bucket regions ----------------
__global__ void __launch_bounds__(256) xscatter_kernel(
        const int* __restrict__ eu, const int* __restrict__ ei,
        const float* __restrict__ vui, const float* __restrict__ viu,
        const int* __restrict__ bbase, int* __restrict__ bfill,
        int2* __restrict__ staging, int phase) {
    int cls = blockIdx.x & 7;
    int sub = blockIdx.x >> 3;           // 0..255
    for (int t = sub * 256 + (int)threadIdx.x; t < NEDGE; t += 256 * 256) {
        int u = __builtin_nontemporal_load(&eu[t]);
        int i = __builtin_nontemporal_load(&ei[t]);
        float va = __builtin_nontemporal_load(&vui[t]);
        float vb = __builtin_nontemporal_load(&viu[t]);
        int bu = u >> BSH;
        if ((bu & 7) == cls && ((bu >> 3) & 1) == phase) {
            int slot = bbase[bu] + atomicAdd(&bfill[bu * CPAD], 1);
            staging[slot] = make_int2(((u & 63) << 17) | i, __float_as_int(va));
        }
        int bid = NBU + (i >> BSH);
        if ((bid & 7) == cls && ((bid >> 3) & 1) == phase) {
            int slot = bbase[bid] + atomicAdd(&bfill[bid * CPAD], 1);
            staging[slot] = make_int2(((i & 63) << 17) | u, __float_as_int(vb));
        }
    }
}

// ---------------- phase B: per-bucket two-pass: row counts -> rowptr -> row-ordered csr ----------------
__global__ void __launch_bounds__(256) rsort_kernel(const int* __restrict__ bbase,
                                                    const int2* __restrict__ staging,
                                                    int2* __restrict__ csr,
                                                    int* __restrict__ rowptr) {
    __shared__ int fillr[64];
    __shared__ int rp[64];
    int b = blockIdx.x;
    int gRowBase, rows;
    if (b < NBU) {
        gRowBase = b << BSH;
        rows = min(64, U_NUM - gRowBase);
    } else {
        int rb = (b - NBU) << BSH;
        gRowBase = U_NUM + rb;
        rows = min(64, I_NUM - rb);
    }
    if (threadIdx.x < 64) fillr[threadIdx.x] = 0;
    __syncthreads();
    int beg = bbase[b], end = bbase[b + 1];
    // pass 1: per-row counts (LDS atomics)
    for (int e = beg + (int)threadIdx.x; e < end; e += 256) {
        int off = staging[e].x >> 17;
        atomicAdd(&fillr[off], 1);
    }
    __syncthreads();
    // wave 0: inclusive shuffle-scan of 64 counters -> exclusive row bases; publish rowptr
    if (threadIdx.x < 64) {
        int c = fillr[threadIdx.x];
        int inc = c;
#pragma unroll
        for (int o = 1; o < 64; o <<= 1) {
            int x = __shfl_up(inc, o);
            if ((int)threadIdx.x >= o) inc += x;
        }
        int excl = beg + inc - c;
        rp[threadIdx.x] = excl;
        if ((int)threadIdx.x < rows) rowptr[gRowBase + threadIdx.x] = excl;
        fillr[threadIdx.x] = 0;
    }
    if (b == 0 && threadIdx.x == 64) rowptr[NROWS] = TOTSLOTS;
    __syncthreads();
    // pass 2: scatter to row-ordered csr (staging L2-hot from pass 1)
    for (int e = beg + (int)threadIdx.x; e < end; e += 256) {
        int2 pk = staging[e];
        int off = pk.x >> 17;
        int dst = rp[off] + atomicAdd(&fillr[off], 1);
        csr[dst] = make_int2(pk.x & 0x1FFFF, pk.y);
    }
}

// ---------------- propagation: wave per row, register acc, 8-unroll + serial tail ----------------
__global__ void __launch_bounds__(256) agg_kernel(
        const unsigned short* __restrict__ uprev, const unsigned short* __restrict__ iprev,
        unsigned short* __restrict__ unext, unsigned short* __restrict__ inext,
        const float* __restrict__ di, const float* __restrict__ dj,
        const int* __restrict__ rowptr, const int2* __restrict__ csr) {
    int wid = (blockIdx.x * 256 + threadIdx.x) >> 6;
    int lane = threadIdx.x & 63;
    if (wid >= NROWS) return;
    const unsigned short* selfP;
    const unsigned short* srcT;
    unsigned short* dst;
    float dscale;
    if (wid < U_NUM) {
        selfP = uprev + (size_t)wid * FCT;
        srcT = iprev;
        dst = unext + (size_t)wid * FCT;
        dscale = di[wid];
    } else {
        int r = wid - U_NUM;
        selfP = iprev + (size_t)r * FCT;
        srcT = uprev;
        dst = inext + (size_t)r * FCT;
        dscale = dj[r];
    }
    int beg = rowptr[wid], end = rowptr[wid + 1];
    float acc = b2f(selfP[lane]) * dscale;
    int e = beg;
    for (; e + 8 <= end; e += 8) {
        int2 p[8];
        float g[8];
#pragma unroll
        for (int k = 0; k < 8; k++) p[k] = csr[e + k];
#pragma unroll
        for (int k = 0; k < 8; k++) g[k] = b2f(srcT[(size_t)p[k].x * FCT + lane]);
#pragma unroll
        for (int k = 0; k < 8; k++) acc = fmaf(__int_as_float(p[k].y), g[k], acc);
    }
    for (; e < end; ++e) {
        int2 p = csr[e];
        acc = fmaf(__int_as_float(p.y), b2f(srcT[(size_t)p.x * FCT + lane]), acc);
    }
    dst[lane] = f2b(acc);
}

// ---------------- BPR head ----------------
__global__ void __launch_bounds__(256) batch_kernel(
        const float* __restrict__ u0f, const float* __restrict__ i0f,
        const unsigned short* __restrict__ u1, const unsigned short* __restrict__ u2,
        const unsigned short* __restrict__ u3,
        const unsigned short* __restrict__ i1, const unsigned short* __restrict__ i2,
        const unsigned short* __restrict__ i3,
        const int* __restrict__ user, const int* __restrict__ ita, const int* __restrict__ itb,
        float* __restrict__ out, float* __restrict__ ls, float* __restrict__ l2a) {
    int wid = (blockIdx.x * 256 + threadIdx.x) >> 6;
    int lane = threadIdx.x & 63;
    if (wid >= BATCH) return;
    size_t uo = (size_t)user[wid] * FCT + lane;
    size_t ao = (size_t)ita[wid] * FCT + lane;
    size_t bo = (size_t)itb[wid] * FCT + lane;

    float pi, pj, l2;
    {
        float ue = u0f[uo], ie = i0f[ao], je = i0f[bo];
        pi = ue * ie; pj = ue * je; l2 = ue * ue + ie * ie + je * je;
    }
    const unsigned short* Ut[3] = {u1, u2, u3};
    const unsigned short* It[3] = {i1, i2, i3};
#pragma unroll
    for (int l = 0; l < 3; l++) {
        float ue = b2f(Ut[l][uo]), ie = b2f(It[l][ao]), je = b2f(It[l][bo]);
        pi += ue * ie;
        pj += ue * je;
        l2 += ue * ue + ie * ie + je * je;
    }
#pragma unroll
    for (int off = 32; off; off >>= 1) {
        pi += __shfl_xor(pi, off);
        pj += __shfl_xor(pj, off);
        l2 += __shfl_xor(l2, off);
    }
    if (lane == 0) {
        out[wid] = pi;
        out[BATCH + wid] = pj;
        float x = pi - pj;
        ls[wid] = fminf(x, 0.0f) - log1pf(expf(-fabsf(x)));
        l2a[wid] = 0.01f * l2;
    }
}

__global__ void final_kernel(const float* __restrict__ ls, const float* __restrict__ l2a,
                             float* __restrict__ out) {
    __shared__ float s1[256], s2[256];
    int t = threadIdx.x;
    float a = 0.f, b = 0.f;
    for (int i = t; i < BATCH; i += 256) {
        a += ls[i];
        b += l2a[i];
    }
    s1[t] = a;
    s2[t] = b;
    __syncthreads();
    for (int off = 128; off; off >>= 1) {
        if (t < off) {
            s1[t] += s1[t + off];
            s2[t] += s2[t + off];
        }
        __syncthreads();
    }
    if (t == 0) {
        float loss2 = -s1[0] / (float)BATCH;
        float l2m = s2[0] / (float)BATCH;
        out[2 * BATCH] = loss2 + l2m;
        out[2 * BATCH + 1] = loss2;
    }
}

// ---------------- launch ----------------
extern "C" void kernel_launch(void* const* d_in, const int* in_sizes, int n_in,
                              void* d_out, int out_size, void* d_ws, size_t ws_size,
                              hipStream_t stream) {
    const float* u0f = (const float*)d_in[0];
    const float* i0f = (const float*)d_in[1];
    const float* di  = (const float*)d_in[2];
    const float* dj  = (const float*)d_in[3];
    const float* vui = (const float*)d_in[4];
    const float* viu = (const float*)d_in[5];
    const int*   eu  = (const int*)d_in[6];
    const int*   ei  = (const int*)d_in[7];
    const int*   usr = (const int*)d_in[8];
    const int*   ita = (const int*)d_in[9];
    const int*   itb = (const int*)d_in[10];
    float* out = (float*)d_out;

    char* p = (char*)d_ws;
    auto alloc = [&](size_t bytes) -> char* {
        char* r = p;
        p += (bytes + 255) & ~(size_t)255;
        return r;
    };
    unsigned short* u0b = (unsigned short*)alloc((size_t)U_NUM * FCT * 2);
    unsigned short* u1b = (unsigned short*)alloc((size_t)U_NUM * FCT * 2);
    unsigned short* i0b = (unsigned short*)alloc((size_t)I_NUM * FCT * 2);
    unsigned short* i1b = (unsigned short*)alloc((size_t)I_NUM * FCT * 2);
    int2* csr     = (int2*)alloc((size_t)TOTSLOTS * 8);          // 51.2 MB
    int2* staging = (int2*)alloc((size_t)TOTSLOTS * 8);          // 51.2 MB
    int* rowptr = (int*)alloc((size_t)(NROWS + 1) * 4);
    int* bcnt8  = (int*)alloc((size_t)8 * NBUCK * 4);            // 75 KB
    int* bbase  = (int*)alloc((size_t)(NBUCK + 1) * 4);
    int* bfill  = (int*)alloc((size_t)NBUCK * CPAD * 4);
    float* ls   = (float*)alloc((size_t)BATCH * 4);
    float* l2a  = (float*)alloc((size_t)BATCH * 4);
    // overlay levels 2,3 on staging (dead after rsort; written by later agg launches)
    unsigned short* u2b = (unsigned short*)staging;
    unsigned short* u3b = u2b + (size_t)U_NUM * FCT;
    unsigned short* i2b = u3b + (size_t)U_NUM * FCT;
    unsigned short* i3b = i2b + (size_t)I_NUM * FCT;

    hipMemsetAsync(bcnt8, 0, (size_t)8 * NBUCK * 4, stream);
    hipMemsetAsync(bfill, 0, (size_t)NBUCK * CPAD * 4, stream);

    conv_kernel<<<(U_NUM * FCT / 4 + 255) / 256, 256, 0, stream>>>(u0f, u0b, U_NUM * FCT / 4);
    conv_kernel<<<(I_NUM * FCT / 4 + 255) / 256, 256, 0, stream>>>(i0f, i0b, I_NUM * FCT / 4);

    bhist_kernel<<<512, 256, 0, stream>>>(eu, ei, bcnt8);
    bscan_kernel<<<1, 256, 0, stream>>>(bcnt8, bbase);

    xscatter_kernel<<<2048, 256, 0, stream>>>(eu, ei, vui, viu, bbase, bfill, staging, 0);
    xscatter_kernel<<<2048, 256, 0, stream>>>(eu, ei, vui, viu, bbase, bfill, staging, 1);
    rsort_kernel<<<NBUCK, 256, 0, stream>>>(bbase, staging, csr, rowptr);

    int aggGrid = (NROWS * 64) / 256 + 1;
    agg_kernel<<<aggGrid, 256, 0, stream>>>(u0b, i0b, u1b, i1b, di, dj, rowptr, csr);
    agg_kernel<<<aggGrid, 256, 0, stream>>>(u1b, i1b, u2b, i2b, di, dj, rowptr, csr);
    agg_kernel<<<aggGrid, 256, 0, stream>>>(u2b, i2b, u3b, i3b, di, dj, rowptr, csr);

    batch_kernel<<<(BATCH * 64) / 256, 256, 0, stream>>>(u0f, i0f, u1b, u2b, u3b,
                                                         i1b, i2b, i3b,
                                                         usr, ita, itb, out, ls, l2a);
    final_kernel<<<1, 256, 0, stream>>>(ls, l2a, out);
}

// Round 10
// 765.002 us; speedup vs baseline: 2.0674x; 1.3552x over previous
//
#include <hip/hip_runtime.h>

#define U_NUM   100000
#define I_NUM   50000
#define FCT     64
#define NEDGE   3200000
#define BATCH   16384
#define NROWS   (U_NUM + I_NUM)      // 150000
#define TOTSLOTS (2 * NEDGE)         // 6400000

#define BSH 6                        // 64 rows per bucket
#define NBU 1563                     // ceil(100000/64)
#define NBI 782                      // ceil(50000/64)
#define NBUCK (NBU + NBI)            // 2345
#define NQ   294                     // ceil(NBUCK/8) buckets per class
#define SUBS 256                     // blocks per class in scatter grid

__device__ __forceinline__ unsigned short f2b(float f) {
    unsigned int x = __float_as_uint(f);
    unsigned int r = (x + 0x7FFFu + ((x >> 16) & 1u)) >> 16;   // RNE
    return (unsigned short)r;
}
__device__ __forceinline__ float b2f(unsigned short u) {
    return __uint_as_float(((unsigned int)u) << 16);
}

// ---------------- fp32 -> bf16 table conversion ----------------
__global__ void conv_kernel(const float* __restrict__ in, unsigned short* __restrict__ out, int n4) {
    int t = blockIdx.x * blockDim.x + threadIdx.x;
    if (t >= n4) return;
    float4 v = *reinterpret_cast<const float4*>(in + (size_t)t * 4);
    ushort4 o;
    o.x = f2b(v.x); o.y = f2b(v.y); o.z = f2b(v.z); o.w = f2b(v.w);
    *reinterpret_cast<ushort4*>(out + (size_t)t * 4) = o;
}

// ---------------- bucket histogram: LDS-private count, flush to class copy ----------------
__global__ void __launch_bounds__(256) bhist_kernel(const int* __restrict__ eu,
                                                    const int* __restrict__ ei,
                                                    int* __restrict__ bcnt8) {
    __shared__ int lcnt[NBUCK];
    for (int k = threadIdx.x; k < NBUCK; k += 256) lcnt[k] = 0;
    __syncthreads();
    int stride = gridDim.x * 256;
    for (int t = blockIdx.x * 256 + (int)threadIdx.x; t < NEDGE; t += stride) {
        int u = eu[t];
        int i = ei[t];
        atomicAdd(&lcnt[u >> BSH], 1);
        atomicAdd(&lcnt[NBU + (i >> BSH)], 1);
    }
    __syncthreads();
    int* mycnt = bcnt8 + (size_t)(blockIdx.x & 7) * NBUCK;
    for (int k = threadIdx.x; k < NBUCK; k += 256) {
        int v = lcnt[k];
        if (v) atomicAdd(&mycnt[k], v);
    }
}

// ---------------- single-block exclusive scan over NBUCK buckets (sums 8 copies) ----------------
__global__ void bscan_kernel(const int* __restrict__ bcnt8, int* __restrict__ bbase) {
    __shared__ int s[256];
    int t = threadIdx.x;
    int v[10];                          // 256*10 = 2560 >= NBUCK
    int tot = 0;
#pragma unroll
    for (int k = 0; k < 10; k++) {
        int idx = t * 10 + k;
        int c = 0;
        if (idx < NBUCK) {
#pragma unroll
            for (int x = 0; x < 8; x++) c += bcnt8[(size_t)x * NBUCK + idx];
        }
        v[k] = c;
        tot += c;
    }
    s[t] = tot;
    __syncthreads();
    for (int off = 1; off < 256; off <<= 1) {
        int x = (t >= off) ? s[t - off] : 0;
        __syncthreads();
        s[t] += x;
        __syncthreads();
    }
    int p = s[t] - tot;
#pragma unroll
    for (int k = 0; k < 10; k++) {
        int idx = t * 10 + k;
        if (idx < NBUCK) bbase[idx] = p;
        p += v[k];
    }
    if (t == 255) bbase[NBUCK] = TOTSLOTS;
}

// ---------------- multisplit pass 1: per-(block,bucket) counts, zero global atomics ----------------
// Block = (cls, sub). Counts class-matching appends per bucket (q = bucket>>3) in LDS,
// writes its NQ-int count row CONTIGUOUSLY to cntmat[(cls*SUBS+sub)*NQ + q].
__global__ void __launch_bounds__(256) countA_kernel(const int* __restrict__ eu,
                                                     const int* __restrict__ ei,
                                                     int* __restrict__ cntmat) {
    __shared__ int lcnt[NQ];
    for (int k = threadIdx.x; k < NQ; k += 256) lcnt[k] = 0;
    __syncthreads();
    int cls = blockIdx.x & 7;
    int sub = blockIdx.x >> 3;
    for (int t = sub * 256 + (int)threadIdx.x; t < NEDGE; t += SUBS * 256) {
        int u = eu[t];
        int i = ei[t];
        int bu = u >> BSH;
        if ((bu & 7) == cls) atomicAdd(&lcnt[bu >> 3], 1);
        int bid = NBU + (i >> BSH);
        if ((bid & 7) == cls) atomicAdd(&lcnt[bid >> 3], 1);
    }
    __syncthreads();
    int* row = cntmat + (size_t)(cls * SUBS + sub) * NQ;
    for (int k = threadIdx.x; k < NQ; k += 256) row[k] = lcnt[k];
}

// ---------------- multisplit pass 2: per-bucket scan of block counts -> basemat ----------------
// Block b (bucket): exclusive scan over sub=0..255 of cntmat[(cls*SUBS+sub)*NQ+q], + bbase[b].
__global__ void __launch_bounds__(256) bscan2_kernel(const int* __restrict__ cntmat,
                                                     const int* __restrict__ bbase,
                                                     int* __restrict__ basemat) {
    __shared__ int ws[4];
    int b = blockIdx.x;
    int cls = b & 7, q = b >> 3;
    int t = threadIdx.x;
    size_t idx = (size_t)(cls * SUBS + t) * NQ + q;
    int c = cntmat[idx];
    int inc = c;
#pragma unroll
    for (int o = 1; o < 64; o <<= 1) {
        int x = __shfl_up(inc, o);
        if ((t & 63) >= o) inc += x;
    }
    if ((t & 63) == 63) ws[t >> 6] = inc;
    __syncthreads();
    int carry = 0;
#pragma unroll
    for (int w = 0; w < 4; w++) {
        if ((t >> 6) > w) carry += ws[w];
    }
    basemat[idx] = bbase[b] + carry + inc - c;   // exclusive
}

// ---------------- multisplit pass 3: rank-scatter, contiguous runs, zero global atomics ----------------
__global__ void __launch_bounds__(256) scatterB_kernel(const int* __restrict__ eu,
                                                       const int* __restrict__ ei,
                                                       const float* __restrict__ vui,
                                                       const float* __restrict__ viu,
                                                       const int* __restrict__ basemat,
                                                       int2* __restrict__ staging) {
    __shared__ int lbase[NQ];
    __shared__ int lrank[NQ];
    int cls = blockIdx.x & 7;
    int sub = blockIdx.x >> 3;
    const int* row = basemat + (size_t)(cls * SUBS + sub) * NQ;
    for (int k = threadIdx.x; k < NQ; k += 256) {
        lbase[k] = row[k];
        lrank[k] = 0;
    }
    __syncthreads();
    for (int t = sub * 256 + (int)threadIdx.x; t < NEDGE; t += SUBS * 256) {
        int u = eu[t];
        int i = ei[t];
        int bu = u >> BSH;
        if ((bu & 7) == cls) {
            float va = vui[t];
            int q = bu >> 3;
            int r = atomicAdd(&lrank[q], 1);
            staging[lbase[q] + r] = make_int2(((u & 63) << 17) | i, __float_as_int(va));
        }
        int bid = NBU + (i >> BSH);
        if ((bid & 7) == cls) {
            float vb = viu[t];
            int q = bid >> 3;
            int r = atomicAdd(&lrank[q], 1);
            staging[lbase[q] + r] = make_int2(((i & 63) << 17) | u, __float_as_int(vb));
        }
    }
}

// ---------------- phase B: per-bucket two-pass: row counts -> rowptr -> row-ordered csr ----------------
__global__ void __launch_bounds__(256) rsort_kernel(const int* __restrict__ bbase,
                                                    const int2* __restrict__ staging,
                                                    int2* __restrict__ csr,
                                                    int* __restrict__ rowptr) {
    __shared__ int fillr[64];
    __shared__ int rp[64];
    int b = blockIdx.x;
    int gRowBase, rows;
    if (b < NBU) {
        gRowBase = b << BSH;
        rows = min(64, U_NUM - gRowBase);
    } else {
        int rb = (b - NBU) << BSH;
        gRowBase = U_NUM + rb;
        rows = min(64, I_NUM - rb);
    }
    if (threadIdx.x < 64) fillr[threadIdx.x] = 0;
    __syncthreads();
    int beg = bbase[b], end = bbase[b + 1];
    // pass 1: per-row counts (LDS atomics)
    for (int e = beg + (int)threadIdx.x; e < end; e += 256) {
        int off = staging[e].x >> 17;
        atomicAdd(&fillr[off], 1);
    }
    __syncthreads();
    // wave 0: inclusive shuffle-scan of 64 counters -> exclusive row bases; publish rowptr
    if (threadIdx.x < 64) {
        int c = fillr[threadIdx.x];
        int inc = c;
#pragma unroll
        for (int o = 1; o < 64; o <<= 1) {
            int x = __shfl_up(inc, o);
            if ((int)threadIdx.x >= o) inc += x;
        }
        int excl = beg + inc - c;
        rp[threadIdx.x] = excl;
        if ((int)threadIdx.x < rows) rowptr[gRowBase + threadIdx.x] = excl;
        fillr[threadIdx.x] = 0;
    }
    if (b == 0 && threadIdx.x == 64) rowptr[NROWS] = TOTSLOTS;
    __syncthreads();
    // pass 2: scatter to row-ordered csr (staging L2-hot from pass 1)
    for (int e = beg + (int)threadIdx.x; e < end; e += 256) {
        int2 pk = staging[e];
        int off = pk.x >> 17;
        int dst = rp[off] + atomicAdd(&fillr[off], 1);
        csr[dst] = make_int2(pk.x & 0x1FFFF, pk.y);
    }
}

// ---------------- propagation: wave per row, register acc, 8-unroll + serial tail ----------------
__global__ void __launch_bounds__(256) agg_kernel(
        const unsigned short* __restrict__ uprev, const unsigned short* __restrict__ iprev,
        unsigned short* __restrict__ unext, unsigned short* __restrict__ inext,
        const float* __restrict__ di, const float* __restrict__ dj,
        const int* __restrict__ rowptr, const int2* __restrict__ csr) {
    int wid = (blockIdx.x * 256 + threadIdx.x) >> 6;
    int lane = threadIdx.x & 63;
    if (wid >= NROWS) return;
    const unsigned short* selfP;
    const unsigned short* srcT;
    unsigned short* dst;
    float dscale;
    if (wid < U_NUM) {
        selfP = uprev + (size_t)wid * FCT;
        srcT = iprev;
        dst = unext + (size_t)wid * FCT;
        dscale = di[wid];
    } else {
        int r = wid - U_NUM;
        selfP = iprev + (size_t)r * FCT;
        srcT = uprev;
        dst = inext + (size_t)r * FCT;
        dscale = dj[r];
    }
    int beg = rowptr[wid], end = rowptr[wid + 1];
    float acc = b2f(selfP[lane]) * dscale;
    int e = beg;
    for (; e + 8 <= end; e += 8) {
        int2 p[8];
        float g[8];
#pragma unroll
        for (int k = 0; k < 8; k++) p[k] = csr[e + k];
#pragma unroll
        for (int k = 0; k < 8; k++) g[k] = b2f(srcT[(size_t)p[k].x * FCT + lane]);
#pragma unroll
        for (int k = 0; k < 8; k++) acc = fmaf(__int_as_float(p[k].y), g[k], acc);
    }
    for (; e < end; ++e) {
        int2 p = csr[e];
        acc = fmaf(__int_as_float(p.y), b2f(srcT[(size_t)p.x * FCT + lane]), acc);
    }
    dst[lane] = f2b(acc);
}

// ---------------- BPR head ----------------
__global__ void __launch_bounds__(256) batch_kernel(
        const float* __restrict__ u0f, const float* __restrict__ i0f,
        const unsigned short* __restrict__ u1, const unsigned short* __restrict__ u2,
        const unsigned short* __restrict__ u3,
        const unsigned short* __restrict__ i1, const unsigned short* __restrict__ i2,
        const unsigned short* __restrict__ i3,
        const int* __restrict__ user, const int* __restrict__ ita, const int* __restrict__ itb,
        float* __restrict__ out, float* __restrict__ ls, float* __restrict__ l2a) {
    int wid = (blockIdx.x * 256 + threadIdx.x) >> 6;
    int lane = threadIdx.x & 63;
    if (wid >= BATCH) return;
    size_t uo = (size_t)user[wid] * FCT + lane;
    size_t ao = (size_t)ita[wid] * FCT + lane;
    size_t bo = (size_t)itb[wid] * FCT + lane;

    float pi, pj, l2;
    {
        float ue = u0f[uo], ie = i0f[ao], je = i0f[bo];
        pi = ue * ie; pj = ue * je; l2 = ue * ue + ie * ie + je * je;
    }
    const unsigned short* Ut[3] = {u1, u2, u3};
    const unsigned short* It[3] = {i1, i2, i3};
#pragma unroll
    for (int l = 0; l < 3; l++) {
        float ue = b2f(Ut[l][uo]), ie = b2f(It[l][ao]), je = b2f(It[l][bo]);
        pi += ue * ie;
        pj += ue * je;
        l2 += ue * ue + ie * ie + je * je;
    }
#pragma unroll
    for (int off = 32; off; off >>= 1) {
        pi += __shfl_xor(pi, off);
        pj += __shfl_xor(pj, off);
        l2 += __shfl_xor(l2, off);
    }
    if (lane == 0) {
        out[wid] = pi;
        out[BATCH + wid] = pj;
        float x = pi - pj;
        ls[wid] = fminf(x, 0.0f) - log1pf(expf(-fabsf(x)));
        l2a[wid] = 0.01f * l2;
    }
}

__global__ void final_kernel(const float* __restrict__ ls, const float* __restrict__ l2a,
                             float* __restrict__ out) {
    __shared__ float s1[256], s2[256];
    int t = threadIdx.x;
    float a = 0.f, b = 0.f;
    for (int i = t; i < BATCH; i += 256) {
        a += ls[i];
        b += l2a[i];
    }
    s1[t] = a;
    s2[t] = b;
    __syncthreads();
    for (int off = 128; off; off >>= 1) {
        if (t < off) {
            s1[t] += s1[t + off];
            s2[t] += s2[t + off];
        }
        __syncthreads();
    }
    if (t == 0) {
        float loss2 = -s1[0] / (float)BATCH;
        float l2m = s2[0] / (float)BATCH;
        out[2 * BATCH] = loss2 + l2m;
        out[2 * BATCH + 1] = loss2;
    }
}

// ---------------- launch ----------------
extern "C" void kernel_launch(void* const* d_in, const int* in_sizes, int n_in,
                              void* d_out, int out_size, void* d_ws, size_t ws_size,
                              hipStream_t stream) {
    const float* u0f = (const float*)d_in[0];
    const float* i0f = (const float*)d_in[1];
    const float* di  = (const float*)d_in[2];
    const float* dj  = (const float*)d_in[3];
    const float* vui = (const float*)d_in[4];
    const float* viu = (const float*)d_in[5];
    const int*   eu  = (const int*)d_in[6];
    const int*   ei  = (const int*)d_in[7];
    const int*   usr = (const int*)d_in[8];
    const int*   ita = (const int*)d_in[9];
    const int*   itb = (const int*)d_in[10];
    float* out = (float*)d_out;

    char* p = (char*)d_ws;
    auto alloc = [&](size_t bytes) -> char* {
        char* r = p;
        p += (bytes + 255) & ~(size_t)255;
        return r;
    };
    unsigned short* u0b = (unsigned short*)alloc((size_t)U_NUM * FCT * 2);
    unsigned short* u1b = (unsigned short*)alloc((size_t)U_NUM * FCT * 2);
    unsigned short* i0b = (unsigned short*)alloc((size_t)I_NUM * FCT * 2);
    unsigned short* i1b = (unsigned short*)alloc((size_t)I_NUM * FCT * 2);
    int2* csr     = (int2*)alloc((size_t)TOTSLOTS * 8);          // 51.2 MB
    int2* staging = (int2*)alloc((size_t)TOTSLOTS * 8);          // 51.2 MB
    int* rowptr  = (int*)alloc((size_t)(NROWS + 1) * 4);
    int* bcnt8   = (int*)alloc((size_t)8 * NBUCK * 4);           // 75 KB
    int* bbase   = (int*)alloc((size_t)(NBUCK + 1) * 4);
    int* cntmat  = (int*)alloc((size_t)8 * SUBS * NQ * 4);       // 2.4 MB
    int* basemat = (int*)alloc((size_t)8 * SUBS * NQ * 4);       // 2.4 MB
    float* ls    = (float*)alloc((size_t)BATCH * 4);
    float* l2a   = (float*)alloc((size_t)BATCH * 4);
    // overlay levels 2,3 on staging (dead after rsort; written by later agg launches)
    unsigned short* u2b = (unsigned short*)staging;
    unsigned short* u3b = u2b + (size_t)U_NUM * FCT;
    unsigned short* i2b = u3b + (size_t)U_NUM * FCT;
    unsigned short* i3b = i2b + (size_t)I_NUM * FCT;

    hipMemsetAsync(bcnt8, 0, (size_t)8 * NBUCK * 4, stream);

    conv_kernel<<<(U_NUM * FCT / 4 + 255) / 256, 256, 0, stream>>>(u0f, u0b, U_NUM * FCT / 4);
    conv_kernel<<<(I_NUM * FCT / 4 + 255) / 256, 256, 0, stream>>>(i0f, i0b, I_NUM * FCT / 4);

    bhist_kernel<<<512, 256, 0, stream>>>(eu, ei, bcnt8);
    bscan_kernel<<<1, 256, 0, stream>>>(bcnt8, bbase);

    countA_kernel<<<2048, 256, 0, stream>>>(eu, ei, cntmat);
    bscan2_kernel<<<NBUCK, 256, 0, stream>>>(cntmat, bbase, basemat);
    scatterB_kernel<<<2048, 256, 0, stream>>>(eu, ei, vui, viu, basemat, staging);
    rsort_kernel<<<NBUCK, 256, 0, stream>>>(bbase, staging, csr, rowptr);

    int aggGrid = (NROWS * 64) / 256 + 1;
    agg_kernel<<<aggGrid, 256, 0, stream>>>(u0b, i0b, u1b, i1b, di, dj, rowptr, csr);
    agg_kernel<<<aggGrid, 256, 0, stream>>>(u1b, i1b, u2b, i2b, di, dj, rowptr, csr);
    agg_kernel<<<aggGrid, 256, 0, stream>>>(u2b, i2b, u3b, i3b, di, dj, rowptr, csr);

    batch_kernel<<<(BATCH * 64) / 256, 256, 0, stream>>>(u0f, i0f, u1b, u2b, u3b,
                                                         i1b, i2b, i3b,
                                                         usr, ita, itb, out, ls, l2a);
    final_kernel<<<1, 256, 0, stream>>>(ls, l2a, out);
}

// Round 11
// 758.793 us; speedup vs baseline: 2.0843x; 1.0082x over previous
//
#include <hip/hip_runtime.h>

#define U_NUM   100000
#define I_NUM   50000
#define FCT     64
#define NEDGE   3200000
#define BATCH   16384
#define NROWS   (U_NUM + I_NUM)      // 150000
#define TOTSLOTS (2 * NEDGE)         // 6400000

#define BSH 6                        // 64 rows per bucket
#define NBU 1563                     // ceil(100000/64)
#define NBI 782                      // ceil(50000/64)
#define NBUCK (NBU + NBI)            // 2345
#define NQ   294                     // ceil(NBUCK/8) buckets per class
#define SUBS 256                     // blocks per class in scatter grid
#define BUFSZ 4096                   // LDS payload buffer (expected fill 3125)

__device__ __forceinline__ unsigned short f2b(float f) {
    unsigned int x = __float_as_uint(f);
    unsigned int r = (x + 0x7FFFu + ((x >> 16) & 1u)) >> 16;   // RNE
    return (unsigned short)r;
}
__device__ __forceinline__ float b2f(unsigned short u) {
    return __uint_as_float(((unsigned int)u) << 16);
}

// ---------------- fp32 -> bf16 table conversion ----------------
__global__ void conv_kernel(const float* __restrict__ in, unsigned short* __restrict__ out, int n4) {
    int t = blockIdx.x * blockDim.x + threadIdx.x;
    if (t >= n4) return;
    float4 v = *reinterpret_cast<const float4*>(in + (size_t)t * 4);
    ushort4 o;
    o.x = f2b(v.x); o.y = f2b(v.y); o.z = f2b(v.z); o.w = f2b(v.w);
    *reinterpret_cast<ushort4*>(out + (size_t)t * 4) = o;
}

// ---------------- bucket histogram: LDS-private count, flush to class copy ----------------
__global__ void __launch_bounds__(256) bhist_kernel(const int* __restrict__ eu,
                                                    const int* __restrict__ ei,
                                                    int* __restrict__ bcnt8) {
    __shared__ int lcnt[NBUCK];
    for (int k = threadIdx.x; k < NBUCK; k += 256) lcnt[k] = 0;
    __syncthreads();
    int stride = gridDim.x * 256;
    for (int t = blockIdx.x * 256 + (int)threadIdx.x; t < NEDGE; t += stride) {
        int u = eu[t];
        int i = ei[t];
        atomicAdd(&lcnt[u >> BSH], 1);
        atomicAdd(&lcnt[NBU + (i >> BSH)], 1);
    }
    __syncthreads();
    int* mycnt = bcnt8 + (size_t)(blockIdx.x & 7) * NBUCK;
    for (int k = threadIdx.x; k < NBUCK; k += 256) {
        int v = lcnt[k];
        if (v) atomicAdd(&mycnt[k], v);
    }
}

// ---------------- single-block exclusive scan over NBUCK buckets (sums 8 copies) ----------------
__global__ void bscan_kernel(const int* __restrict__ bcnt8, int* __restrict__ bbase) {
    __shared__ int s[256];
    int t = threadIdx.x;
    int v[10];                          // 256*10 = 2560 >= NBUCK
    int tot = 0;
#pragma unroll
    for (int k = 0; k < 10; k++) {
        int idx = t * 10 + k;
        int c = 0;
        if (idx < NBUCK) {
#pragma unroll
            for (int x = 0; x < 8; x++) c += bcnt8[(size_t)x * NBUCK + idx];
        }
        v[k] = c;
        tot += c;
    }
    s[t] = tot;
    __syncthreads();
    for (int off = 1; off < 256; off <<= 1) {
        int x = (t >= off) ? s[t - off] : 0;
        __syncthreads();
        s[t] += x;
        __syncthreads();
    }
    int p = s[t] - tot;
#pragma unroll
    for (int k = 0; k < 10; k++) {
        int idx = t * 10 + k;
        if (idx < NBUCK) bbase[idx] = p;
        p += v[k];
    }
    if (t == 255) bbase[NBUCK] = TOTSLOTS;
}

// ---------------- multisplit pass 1: per-(block,bucket) counts, zero global atomics ----------------
__global__ void __launch_bounds__(256) countA_kernel(const int* __restrict__ eu,
                                                     const int* __restrict__ ei,
                                                     int* __restrict__ cntmat) {
    __shared__ int lcnt[NQ];
    for (int k = threadIdx.x; k < NQ; k += 256) lcnt[k] = 0;
    __syncthreads();
    int cls = blockIdx.x & 7;
    int sub = blockIdx.x >> 3;
    for (int t = sub * 256 + (int)threadIdx.x; t < NEDGE; t += SUBS * 256) {
        int u = eu[t];
        int i = ei[t];
        int bu = u >> BSH;
        if ((bu & 7) == cls) atomicAdd(&lcnt[bu >> 3], 1);
        int bid = NBU + (i >> BSH);
        if ((bid & 7) == cls) atomicAdd(&lcnt[bid >> 3], 1);
    }
    __syncthreads();
    int* row = cntmat + (size_t)(cls * SUBS + sub) * NQ;
    for (int k = threadIdx.x; k < NQ; k += 256) row[k] = lcnt[k];
}

// ---------------- multisplit pass 2: per-bucket scan of block counts -> basemat ----------------
__global__ void __launch_bounds__(256) bscan2_kernel(const int* __restrict__ cntmat,
                                                     const int* __restrict__ bbase,
                                                     int* __restrict__ basemat) {
    __shared__ int ws[4];
    int b = blockIdx.x;
    int cls = b & 7, q = b >> 3;
    int t = threadIdx.x;
    size_t idx = (size_t)(cls * SUBS + t) * NQ + q;
    int c = cntmat[idx];
    int inc = c;
#pragma unroll
    for (int o = 1; o < 64; o <<= 1) {
        int x = __shfl_up(inc, o);
        if ((t & 63) >= o) inc += x;
    }
    if ((t & 63) == 63) ws[t >> 6] = inc;
    __syncthreads();
    int carry = 0;
#pragma unroll
    for (int w = 0; w < 4; w++) {
        if ((t >> 6) > w) carry += ws[w];
    }
    basemat[idx] = bbase[b] + carry + inc - c;   // exclusive
}

// ---------------- multisplit pass 3: LDS-buffered rank-scatter + coalesced flush ----------------
// Scattered 8B stores cost ~32B writeback each (R10: 199MB for 51MB payload) because
// stores interleave across 294 buckets over a 6.4MB region. Fix: place payloads in an
// LDS buffer laid out run-major (lofs[q] = local scan of this block's counts), then
// flush flat -> consecutive global addresses within each run, in one burst. Boundary
// partial lines are closed by the neighbor sub's flush on the SAME XCD (class pinning).
__global__ void __launch_bounds__(256) scatterB_kernel(const int* __restrict__ eu,
                                                       const int* __restrict__ ei,
                                                       const float* __restrict__ vui,
                                                       const float* __restrict__ viu,
                                                       const int* __restrict__ cntmat,
                                                       const int* __restrict__ basemat,
                                                       int2* __restrict__ staging) {
    __shared__ int lofs[NQ + 1];
    __shared__ int lbase[NQ];
    __shared__ int lrank[NQ];
    __shared__ int2 lbuf[BUFSZ];     // 32 KB
    int cls = blockIdx.x & 7;
    int sub = blockIdx.x >> 3;
    const int* crow = cntmat + (size_t)(cls * SUBS + sub) * NQ;
    const int* brow = basemat + (size_t)(cls * SUBS + sub) * NQ;
    for (int k = threadIdx.x; k < NQ; k += 256) {
        lbase[k] = brow[k];
        lrank[k] = 0;
        lofs[k + 1] = crow[k];
    }
    if (threadIdx.x == 0) lofs[0] = 0;
    __syncthreads();
    // wave 0: inclusive scan of lofs[1..NQ] (5 chunks of 64, carried)
    if (threadIdx.x < 64) {
        int carry = 0;
        for (int c = 0; c < 5; c++) {
            int idx = c * 64 + (int)threadIdx.x + 1;
            int v = (idx <= NQ) ? lofs[idx] : 0;
            int inc = v;
#pragma unroll
            for (int o = 1; o < 64; o <<= 1) {
                int x = __shfl_up(inc, o);
                if ((int)threadIdx.x >= o) inc += x;
            }
            if (idx <= NQ) lofs[idx] = carry + inc;
            carry += __shfl(inc, 63);
        }
    }
    __syncthreads();
    int total = lofs[NQ];
    // sweep edge slice, place payloads into LDS buffer (overflow -> direct store)
    for (int t = sub * 256 + (int)threadIdx.x; t < NEDGE; t += SUBS * 256) {
        int u = eu[t];
        int i = ei[t];
        int bu = u >> BSH;
        if ((bu & 7) == cls) {
            int q = bu >> 3;
            int r = atomicAdd(&lrank[q], 1);
            int2 pay = make_int2(((u & 63) << 17) | i, __float_as_int(vui[t]));
            int pos = lofs[q] + r;
            if (pos < BUFSZ) lbuf[pos] = pay;
            else staging[lbase[q] + r] = pay;
        }
        int bid = NBU + (i >> BSH);
        if ((bid & 7) == cls) {
            int q = bid >> 3;
            int r = atomicAdd(&lrank[q], 1);
            int2 pay = make_int2(((i & 63) << 17) | u, __float_as_int(viu[t]));
            int pos = lofs[q] + r;
            if (pos < BUFSZ) lbuf[pos] = pay;
            else staging[lbase[q] + r] = pay;
        }
    }
    __syncthreads();
    // coalesced flush: flat t -> bucket via binary search on lofs
    int fl = min(total, BUFSZ);
    for (int t = threadIdx.x; t < fl; t += 256) {
        int lo = 0, hi = NQ;
        while (hi - lo > 1) {
            int mid = (lo + hi) >> 1;
            if (lofs[mid] <= t) lo = mid; else hi = mid;
        }
        staging[lbase[lo] + (t - lofs[lo])] = lbuf[t];
    }
}

// ---------------- phase B: per-bucket two-pass: row counts -> rowptr -> row-ordered csr ----------------
__global__ void __launch_bounds__(256) rsort_kernel(const int* __restrict__ bbase,
                                                    const int2* __restrict__ staging,
                                                    int2* __restrict__ csr,
                                                    int* __restrict__ rowptr) {
    __shared__ int fillr[64];
    __shared__ int rp[64];
    int b = blockIdx.x;
    int gRowBase, rows;
    if (b < NBU) {
        gRowBase = b << BSH;
        rows = min(64, U_NUM - gRowBase);
    } else {
        int rb = (b - NBU) << BSH;
        gRowBase = U_NUM + rb;
        rows = min(64, I_NUM - rb);
    }
    if (threadIdx.x < 64) fillr[threadIdx.x] = 0;
    __syncthreads();
    int beg = bbase[b], end = bbase[b + 1];
    for (int e = beg + (int)threadIdx.x; e < end; e += 256) {
        int off = staging[e].x >> 17;
        atomicAdd(&fillr[off], 1);
    }
    __syncthreads();
    if (threadIdx.x < 64) {
        int c = fillr[threadIdx.x];
        int inc = c;
#pragma unroll
        for (int o = 1; o < 64; o <<= 1) {
            int x = __shfl_up(inc, o);
            if ((int)threadIdx.x >= o) inc += x;
        }
        int excl = beg + inc - c;
        rp[threadIdx.x] = excl;
        if ((int)threadIdx.x < rows) rowptr[gRowBase + threadIdx.x] = excl;
        fillr[threadIdx.x] = 0;
    }
    if (b == 0 && threadIdx.x == 64) rowptr[NROWS] = TOTSLOTS;
    __syncthreads();
    for (int e = beg + (int)threadIdx.x; e < end; e += 256) {
        int2 pk = staging[e];
        int off = pk.x >> 17;
        int dst = rp[off] + atomicAdd(&fillr[off], 1);
        csr[dst] = make_int2(pk.x & 0x1FFFF, pk.y);
    }
}

// ---------------- propagation: wave per row, register acc, 8-unroll + serial tail ----------------
__global__ void __launch_bounds__(256) agg_kernel(
        const unsigned short* __restrict__ uprev, const unsigned short* __restrict__ iprev,
        unsigned short* __restrict__ unext, unsigned short* __restrict__ inext,
        const float* __restrict__ di, const float* __restrict__ dj,
        const int* __restrict__ rowptr, const int2* __restrict__ csr) {
    int wid = (blockIdx.x * 256 + threadIdx.x) >> 6;
    int lane = threadIdx.x & 63;
    if (wid >= NROWS) return;
    const unsigned short* selfP;
    const unsigned short* srcT;
    unsigned short* dst;
    float dscale;
    if (wid < U_NUM) {
        selfP = uprev + (size_t)wid * FCT;
        srcT = iprev;
        dst = unext + (size_t)wid * FCT;
        dscale = di[wid];
    } else {
        int r = wid - U_NUM;
        selfP = iprev + (size_t)r * FCT;
        srcT = uprev;
        dst = inext + (size_t)r * FCT;
        dscale = dj[r];
    }
    int beg = rowptr[wid], end = rowptr[wid + 1];
    float acc = b2f(selfP[lane]) * dscale;
    int e = beg;
    for (; e + 8 <= end; e += 8) {
        int2 p[8];
        float g[8];
#pragma unroll
        for (int k = 0; k < 8; k++) p[k] = csr[e + k];
#pragma unroll
        for (int k = 0; k < 8; k++) g[k] = b2f(srcT[(size_t)p[k].x * FCT + lane]);
#pragma unroll
        for (int k = 0; k < 8; k++) acc = fmaf(__int_as_float(p[k].y), g[k], acc);
    }
    for (; e < end; ++e) {
        int2 p = csr[e];
        acc = fmaf(__int_as_float(p.y), b2f(srcT[(size_t)p.x * FCT + lane]), acc);
    }
    dst[lane] = f2b(acc);
}

// ---------------- BPR head ----------------
__global__ void __launch_bounds__(256) batch_kernel(
        const float* __restrict__ u0f, const float* __restrict__ i0f,
        const unsigned short* __restrict__ u1, const unsigned short* __restrict__ u2,
        const unsigned short* __restrict__ u3,
        const unsigned short* __restrict__ i1, const unsigned short* __restrict__ i2,
        const unsigned short* __restrict__ i3,
        const int* __restrict__ user, const int* __restrict__ ita, const int* __restrict__ itb,
        float* __restrict__ out, float* __restrict__ ls, float* __restrict__ l2a) {
    int wid = (blockIdx.x * 256 + threadIdx.x) >> 6;
    int lane = threadIdx.x & 63;
    if (wid >= BATCH) return;
    size_t uo = (size_t)user[wid] * FCT + lane;
    size_t ao = (size_t)ita[wid] * FCT + lane;
    size_t bo = (size_t)itb[wid] * FCT + lane;

    float pi, pj, l2;
    {
        float ue = u0f[uo], ie = i0f[ao], je = i0f[bo];
        pi = ue * ie; pj = ue * je; l2 = ue * ue + ie * ie + je * je;
    }
    const unsigned short* Ut[3] = {u1, u2, u3};
    const unsigned short* It[3] = {i1, i2, i3};
#pragma unroll
    for (int l = 0; l < 3; l++) {
        float ue = b2f(Ut[l][uo]), ie = b2f(It[l][ao]), je = b2f(It[l][bo]);
        pi += ue * ie;
        pj += ue * je;
        l2 += ue * ue + ie * ie + je * je;
    }
#pragma unroll
    for (int off = 32; off; off >>= 1) {
        pi += __shfl_xor(pi, off);
        pj += __shfl_xor(pj, off);
        l2 += __shfl_xor(l2, off);
    }
    if (lane == 0) {
        out[wid] = pi;
        out[BATCH + wid] = pj;
        float x = pi - pj;
        ls[wid] = fminf(x, 0.0f) - log1pf(expf(-fabsf(x)));
        l2a[wid] = 0.01f * l2;
    }
}

__global__ void final_kernel(const float* __restrict__ ls, const float* __restrict__ l2a,
                             float* __restrict__ out) {
    __shared__ float s1[256], s2[256];
    int t = threadIdx.x;
    float a = 0.f, b = 0.f;
    for (int i = t; i < BATCH; i += 256) {
        a += ls[i];
        b += l2a[i];
    }
    s1[t] = a;
    s2[t] = b;
    __syncthreads();
    for (int off = 128; off; off >>= 1) {
        if (t < off) {
            s1[t] += s1[t + off];
            s2[t] += s2[t + off];
        }
        __syncthreads();
    }
    if (t == 0) {
        float loss2 = -s1[0] / (float)BATCH;
        float l2m = s2[0] / (float)BATCH;
        out[2 * BATCH] = loss2 + l2m;
        out[2 * BATCH + 1] = loss2;
    }
}

// ---------------- launch ----------------
extern "C" void kernel_launch(void* const* d_in, const int* in_sizes, int n_in,
                              void* d_out, int out_size, void* d_ws, size_t ws_size,
                              hipStream_t stream) {
    const float* u0f = (const float*)d_in[0];
    const float* i0f = (const float*)d_in[1];
    const float* di  = (const float*)d_in[2];
    const float* dj  = (const float*)d_in[3];
    const float* vui = (const float*)d_in[4];
    const float* viu = (const float*)d_in[5];
    const int*   eu  = (const int*)d_in[6];
    const int*   ei  = (const int*)d_in[7];
    const int*   usr = (const int*)d_in[8];
    const int*   ita = (const int*)d_in[9];
    const int*   itb = (const int*)d_in[10];
    float* out = (float*)d_out;

    char* p = (char*)d_ws;
    auto alloc = [&](size_t bytes) -> char* {
        char* r = p;
        p += (bytes + 255) & ~(size_t)255;
        return r;
    };
    unsigned short* u0b = (unsigned short*)alloc((size_t)U_NUM * FCT * 2);
    unsigned short* u1b = (unsigned short*)alloc((size_t)U_NUM * FCT * 2);
    unsigned short* i0b = (unsigned short*)alloc((size_t)I_NUM * FCT * 2);
    unsigned short* i1b = (unsigned short*)alloc((size_t)I_NUM * FCT * 2);
    int2* csr     = (int2*)alloc((size_t)TOTSLOTS * 8);          // 51.2 MB
    int2* staging = (int2*)alloc((size_t)TOTSLOTS * 8);          // 51.2 MB
    int* rowptr  = (int*)alloc((size_t)(NROWS + 1) * 4);
    int* bcnt8   = (int*)alloc((size_t)8 * NBUCK * 4);           // 75 KB
    int* bbase   = (int*)alloc((size_t)(NBUCK + 1) * 4);
    int* cntmat  = (int*)alloc((size_t)8 * SUBS * NQ * 4);       // 2.4 MB
    int* basemat = (int*)alloc((size_t)8 * SUBS * NQ * 4);       // 2.4 MB
    float* ls    = (float*)alloc((size_t)BATCH * 4);
    float* l2a   = (float*)alloc((size_t)BATCH * 4);
    // overlay levels 2,3 on staging (dead after rsort; written by later agg launches)
    unsigned short* u2b = (unsigned short*)staging;
    unsigned short* u3b = u2b + (size_t)U_NUM * FCT;
    unsigned short* i2b = u3b + (size_t)U_NUM * FCT;
    unsigned short* i3b = i2b + (size_t)I_NUM * FCT;

    hipMemsetAsync(bcnt8, 0, (size_t)8 * NBUCK * 4, stream);

    conv_kernel<<<(U_NUM * FCT / 4 + 255) / 256, 256, 0, stream>>>(u0f, u0b, U_NUM * FCT / 4);
    conv_kernel<<<(I_NUM * FCT / 4 + 255) / 256, 256, 0, stream>>>(i0f, i0b, I_NUM * FCT / 4);

    bhist_kernel<<<512, 256, 0, stream>>>(eu, ei, bcnt8);
    bscan_kernel<<<1, 256, 0, stream>>>(bcnt8, bbase);

    countA_kernel<<<2048, 256, 0, stream>>>(eu, ei, cntmat);
    bscan2_kernel<<<NBUCK, 256, 0, stream>>>(cntmat, bbase, basemat);
    scatterB_kernel<<<2048, 256, 0, stream>>>(eu, ei, vui, viu, cntmat, basemat, staging);
    rsort_kernel<<<NBUCK, 256, 0, stream>>>(bbase, staging, csr, rowptr);

    int aggGrid = (NROWS * 64) / 256 + 1;
    agg_kernel<<<aggGrid, 256, 0, stream>>>(u0b, i0b, u1b, i1b, di, dj, rowptr, csr);
    agg_kernel<<<aggGrid, 256, 0, stream>>>(u1b, i1b, u2b, i2b, di, dj, rowptr, csr);
    agg_kernel<<<aggGrid, 256, 0, stream>>>(u2b, i2b, u3b, i3b, di, dj, rowptr, csr);

    batch_kernel<<<(BATCH * 64) / 256, 256, 0, stream>>>(u0f, i0f, u1b, u2b, u3b,
                                                         i1b, i2b, i3b,
                                                         usr, ita, itb, out, ls, l2a);
    final_kernel<<<1, 256, 0, stream>>>(ls, l2a, out);
}